// Round 6
// baseline (370.618 us; speedup 1.0000x reference)
//
#include <hip/hip_runtime.h>
#include <hip/hip_bf16.h>

typedef __attribute__((ext_vector_type(8))) short bf16x8;
typedef __attribute__((ext_vector_type(4))) float f32x4;

#define GLOAD_LDS16(gptr, lptr) \
  __builtin_amdgcn_global_load_lds((const __attribute__((address_space(1))) void*)(gptr), \
                                   (__attribute__((address_space(3))) void*)(lptr), 16, 0, 0)

__device__ __forceinline__ unsigned short f2b(float f) {
  union { float f; unsigned u; } x; x.f = f;
  unsigned r = x.u + 0x7fffu + ((x.u >> 16) & 1u);
  return (unsigned short)(r >> 16);
}
__device__ __forceinline__ float b2f(unsigned short u) {
  union { unsigned u; float f; } x; x.u = ((unsigned)u) << 16;
  return x.f;
}

// ---------------- fp32 -> bf16 cast ----------------
__global__ void cast_kernel(const float* __restrict__ in, unsigned short* __restrict__ out, int n) {
  const int i = (blockIdx.x * 256 + threadIdx.x) * 4;
  if (i < n) {
    const float4 v = *(const float4*)(in + i);
    ushort4 r;
    r.x = f2b(v.x); r.y = f2b(v.y); r.z = f2b(v.z); r.w = f2b(v.w);
    *(ushort4*)(out + i) = r;
  }
}

// ---------------- GEMM 256x256, BK=64, read-ahead pipelined (frozen at R4) ----------------
template<int OUTF32>
__global__ __launch_bounds__(512, 2)
void gemm256(const unsigned short* __restrict__ A,
             const unsigned short* __restrict__ Bm,
             const float* __restrict__ bias,
             void* __restrict__ Cp,
             int M, int N, int K)
{
  __shared__ __align__(16) char Lds[131072];
  const int t  = threadIdx.x;
  const int l  = t & 63;
  const int w  = t >> 6;
  const int lr = l & 15;
  const int lkb = (l >> 4) << 4;
  const int wr = w >> 2;
  const int wc = w & 3;

  const int nwg = gridDim.x;
  const int wg  = (blockIdx.x & 7) * (nwg >> 3) + (blockIdx.x >> 3);
  const int NBN = N >> 8;
  const int bm = wg / NBN, bn = wg % NBN;

  const int sw3 = (lr & 7) << 4;
  const int ck0 = lkb ^ sw3;
  const int ck1 = (64 | lkb) ^ sw3;

  const int lb0 = t << 4;
  const int lb1 = lb0 + 8192;
  const int d0 = lb0 ^ (((lb0 >> 7) & 7) << 4);
  const int d1 = lb1 ^ (((lb1 >> 7) & 7) << 4);
  const long K2 = (long)K * 2;
  const char* Ab = (const char*)A  + (long)(bm * 256) * K2;
  const char* Bb = (const char*)Bm + (long)(bn * 256) * K2;
  const long s0 = (long)(d0 >> 7) * K2 + (d0 & 127);
  const long s1 = (long)(d1 >> 7) * K2 + (d1 & 127);
  const long hstep = (long)128 * K2;

  auto stageA = [&](int g, int h) {
    char* dst = Lds + (g & 1) * 65536 + h * 16384;
    const char* src = Ab + (long)h * hstep + (long)g * 128;
    GLOAD_LDS16(src + s0, dst + lb0);
    GLOAD_LDS16(src + s1, dst + lb1);
  };
  auto stageB = [&](int g, int h) {
    char* dst = Lds + (g & 1) * 65536 + 32768 + h * 16384;
    const char* src = Bb + (long)h * hstep + (long)g * 128;
    GLOAD_LDS16(src + s0, dst + lb0);
    GLOAD_LDS16(src + s1, dst + lb1);
  };

  f32x4 acc[8][4] = {};
  const int NT = K >> 6;
  const int brow = ((wc & 1) * 64 + lr) << 7;

  bf16x8 af[4][2], blo[2][2], bhi[2][2];

  stageA(0, 0); stageA(0, 1);
  stageB(0, 0); stageB(0, 1);
  stageB(1, 0); stageB(1, 1);
  asm volatile("s_waitcnt vmcnt(4)" ::: "memory");
  __builtin_amdgcn_s_barrier();
  {
    const char* AH0 = Lds + wr * 16384;
    const char* BH0 = Lds + 32768 + (wc >> 1) * 16384;
#pragma unroll
    for (int ni = 0; ni < 2; ++ni) {
      blo[ni][0] = *(const bf16x8*)(BH0 + brow + (ni << 11) + ck0);
      blo[ni][1] = *(const bf16x8*)(BH0 + brow + (ni << 11) + ck1);
    }
#pragma unroll
    for (int mi = 0; mi < 4; ++mi) {
      af[mi][0] = *(const bf16x8*)(AH0 + ((mi * 16 + lr) << 7) + ck0);
      af[mi][1] = *(const bf16x8*)(AH0 + ((mi * 16 + lr) << 7) + ck1);
    }
#pragma unroll
    for (int ni = 0; ni < 2; ++ni) {
      bhi[ni][0] = *(const bf16x8*)(BH0 + brow + ((ni + 2) << 11) + ck0);
      bhi[ni][1] = *(const bf16x8*)(BH0 + brow + ((ni + 2) << 11) + ck1);
    }
  }

  for (int tt = 0; tt < NT; ++tt) {
    const char* SB = Lds + (tt & 1) * 65536;
    const char* AH = SB + wr * 16384;

    if (tt + 1 < NT) { stageA(tt + 1, 0); stageA(tt + 1, 1); }
    __builtin_amdgcn_s_barrier();
    __builtin_amdgcn_sched_barrier(0);
    __builtin_amdgcn_s_setprio(1);
#pragma unroll
    for (int mi = 0; mi < 4; ++mi)
#pragma unroll
      for (int ni = 0; ni < 2; ++ni) {
        acc[mi][ni] = __builtin_amdgcn_mfma_f32_16x16x32_bf16(af[mi][0], blo[ni][0], acc[mi][ni], 0, 0, 0);
        acc[mi][ni] = __builtin_amdgcn_mfma_f32_16x16x32_bf16(af[mi][1], blo[ni][1], acc[mi][ni], 0, 0, 0);
      }
    __builtin_amdgcn_s_setprio(0);
    __builtin_amdgcn_s_barrier();
    __builtin_amdgcn_sched_barrier(0);

    __builtin_amdgcn_s_setprio(1);
#pragma unroll
    for (int mi = 0; mi < 4; ++mi)
#pragma unroll
      for (int ni = 0; ni < 2; ++ni) {
        acc[mi][ni + 2] = __builtin_amdgcn_mfma_f32_16x16x32_bf16(af[mi][0], bhi[ni][0], acc[mi][ni + 2], 0, 0, 0);
        acc[mi][ni + 2] = __builtin_amdgcn_mfma_f32_16x16x32_bf16(af[mi][1], bhi[ni][1], acc[mi][ni + 2], 0, 0, 0);
      }
    __builtin_amdgcn_s_setprio(0);
#pragma unroll
    for (int mi = 0; mi < 4; ++mi) {
      af[mi][0] = *(const bf16x8*)(AH + ((64 + mi * 16 + lr) << 7) + ck0);
      af[mi][1] = *(const bf16x8*)(AH + ((64 + mi * 16 + lr) << 7) + ck1);
    }
    __builtin_amdgcn_s_barrier();
    __builtin_amdgcn_sched_barrier(0);

    asm volatile("s_waitcnt vmcnt(0)" ::: "memory");
    if (tt + 2 < NT) stageB(tt + 2, 0);
    __builtin_amdgcn_s_setprio(1);
#pragma unroll
    for (int mi = 0; mi < 4; ++mi)
#pragma unroll
      for (int ni = 0; ni < 2; ++ni) {
        acc[mi + 4][ni] = __builtin_amdgcn_mfma_f32_16x16x32_bf16(af[mi][0], blo[ni][0], acc[mi + 4][ni], 0, 0, 0);
        acc[mi + 4][ni] = __builtin_amdgcn_mfma_f32_16x16x32_bf16(af[mi][1], blo[ni][1], acc[mi + 4][ni], 0, 0, 0);
      }
    __builtin_amdgcn_s_setprio(0);
    if (tt + 1 < NT) {
      const char* BHn = Lds + ((tt + 1) & 1) * 65536 + 32768 + (wc >> 1) * 16384;
#pragma unroll
      for (int ni = 0; ni < 2; ++ni) {
        blo[ni][0] = *(const bf16x8*)(BHn + brow + (ni << 11) + ck0);
        blo[ni][1] = *(const bf16x8*)(BHn + brow + (ni << 11) + ck1);
      }
    }
    __builtin_amdgcn_s_barrier();
    __builtin_amdgcn_sched_barrier(0);

    if (tt + 2 < NT) stageB(tt + 2, 1);
    __builtin_amdgcn_s_setprio(1);
#pragma unroll
    for (int mi = 0; mi < 4; ++mi)
#pragma unroll
      for (int ni = 0; ni < 2; ++ni) {
        acc[mi + 4][ni + 2] = __builtin_amdgcn_mfma_f32_16x16x32_bf16(af[mi][0], bhi[ni][0], acc[mi + 4][ni + 2], 0, 0, 0);
        acc[mi + 4][ni + 2] = __builtin_amdgcn_mfma_f32_16x16x32_bf16(af[mi][1], bhi[ni][1], acc[mi + 4][ni + 2], 0, 0, 0);
      }
    __builtin_amdgcn_s_setprio(0);
    if (tt + 1 < NT) {
      const char* SBn = Lds + ((tt + 1) & 1) * 65536;
      const char* AHn = SBn + wr * 16384;
      const char* BHn = SBn + 32768 + (wc >> 1) * 16384;
#pragma unroll
      for (int mi = 0; mi < 4; ++mi) {
        af[mi][0] = *(const bf16x8*)(AHn + ((mi * 16 + lr) << 7) + ck0);
        af[mi][1] = *(const bf16x8*)(AHn + ((mi * 16 + lr) << 7) + ck1);
      }
#pragma unroll
      for (int ni = 0; ni < 2; ++ni) {
        bhi[ni][0] = *(const bf16x8*)(BHn + brow + ((ni + 2) << 11) + ck0);
        bhi[ni][1] = *(const bf16x8*)(BHn + brow + ((ni + 2) << 11) + ck1);
      }
    }
    __builtin_amdgcn_s_barrier();
    __builtin_amdgcn_sched_barrier(0);
  }

  const int roff = (l >> 4) << 2;
  const int row0 = bm * 256 + wr * 128 + roff;
  const int col0 = bn * 256 + wc * 64 + lr;
#pragma unroll
  for (int ni = 0; ni < 4; ++ni) {
    const int col = col0 + ni * 16;
    const float bv = bias ? bias[col] : 0.0f;
#pragma unroll
    for (int mi = 0; mi < 8; ++mi) {
#pragma unroll
      for (int r = 0; r < 4; ++r) {
        const int row = row0 + mi * 16 + r;
        const float v = acc[mi][ni][r] + bv;
        if (OUTF32) ((float*)Cp)[(long)row * N + col] = v;
        else ((unsigned short*)Cp)[(long)row * N + col] = f2b(v);
      }
    }
  }
}

// ---------------- RoPE: qkv[B][T][3][H*128] -> Qr,Kr (B,H,T,D) bf16 ----------------
__global__ void rope_kernel(const unsigned short* __restrict__ qkv,
                            unsigned short* __restrict__ Qr,
                            unsigned short* __restrict__ Kr)
{
  const int T = 2048;
  const int idx = blockIdx.x * 256 + threadIdx.x;
  const int d  = idx & 63;
  const int tt = (idx >> 6) & (T - 1);
  const int bh = idx >> 17;
  const int b = bh >> 4, h = bh & 15;
  const long base = ((long)(b * T + tt) * 3) * 2048 + h * 128;
  const float inv = exp2f(-(float)d * 0.2076205059304602f);
  const float fr = (float)tt * inv;
  float sn, cs;
  sincosf(fr, &sn, &cs);
  const float q1 = b2f(qkv[base + 2 * d]);
  const float q2 = b2f(qkv[base + 2 * d + 1]);
  const float k1 = b2f(qkv[base + 2048 + 2 * d]);
  const float k2 = b2f(qkv[base + 2048 + 2 * d + 1]);
  const long ob = ((long)bh * T + tt) * 128;
  Qr[ob + d]      = f2b(q1 * cs - q2 * sn);
  Qr[ob + 64 + d] = f2b(q1 * sn + q2 * cs);
  Kr[ob + d]      = f2b(k1 * cs - k2 * sn);
  Kr[ob + 64 + d] = f2b(k1 * sn + k2 * cs);
}

// ---------------- V transpose: qkv(...,s=2,...) -> Vt (B,H,D,T) bf16 ----------------
__global__ void vtrans_kernel(const unsigned short* __restrict__ qkv,
                              unsigned short* __restrict__ Vt)
{
  const int T = 2048;
  __shared__ unsigned short ld[128][65];
  const int bh = blockIdx.y, tt = blockIdx.x;
  const int b = bh >> 4, h = bh & 15;
  const int t = threadIdx.x;
#pragma unroll
  for (int i = 0; i < 32; ++i) {
    const int idx = i * 256 + t;
    const int d = idx & 127, tr = idx >> 7;
    ld[d][tr] = qkv[((long)(b * T + tt * 64 + tr) * 3 + 2) * 2048 + h * 128 + d];
  }
  __syncthreads();
#pragma unroll
  for (int i = 0; i < 32; ++i) {
    const int idx = i * 256 + t;
    const int tc = idx & 63, dr = idx >> 6;
    Vt[((long)bh * 128 + dr) * T + tt * 64 + tc] = ld[dr][tc];
  }
}

// ---------------- causal flash attention, 2 q-strips per block ----------------
// grid (B*H, T/128), qt reversed; 4 waves; each wave owns rows q0a=qt*128+w*16
// and q0b=q0a+64. One staged K/V tile feeds both strips (halved staging/sync
// per unit work). KV tile = 64; dbuf + XOR swizzle as verified in R2.
__global__ __launch_bounds__(256)
void attn_fwd(const unsigned short* __restrict__ Q,
              const unsigned short* __restrict__ Kg,
              const unsigned short* __restrict__ Vt,
              unsigned short* __restrict__ O, int T)
{
  __shared__ __align__(16) unsigned short Ks[2][64 * 128];
  __shared__ __align__(16) unsigned short Vs[2][128 * 64];
  __shared__ __align__(16) unsigned short Ps[4][16 * 64];
  const int t = threadIdx.x;
  const int w = t >> 6, l = t & 63;
  const int lr = l & 15;
  const int g16 = (l >> 4) << 4;
  const int sw = (lr & 7) << 4;
  const int bh = blockIdx.x;
  const int qt = (gridDim.y - 1) - blockIdx.y;
  const int q0a = qt * 128 + w * 16;
  const int q0b = q0a + 64;
  const long hbase = (long)bh * T * 128;
  const long hbase2 = hbase * 2;
  const long T2 = (long)T * 2;
  const int roff = (l >> 4) << 2;
  // exp2-domain scale: 1/sqrt(128) * log2(e)
  const float C1 = 0.08838834764831845f * 1.4426950408889634f;

  bf16x8 qfA[4], qfB[4];
  {
    const unsigned short* QrowA = Q + hbase + (long)(q0a + lr) * 128;
    const unsigned short* QrowB = Q + hbase + (long)(q0b + lr) * 128;
#pragma unroll
    for (int ds = 0; ds < 4; ++ds) {
      qfA[ds] = *(const bf16x8*)&QrowA[ds * 32 + (g16 >> 1)];
      qfB[ds] = *(const bf16x8*)&QrowB[ds * 32 + (g16 >> 1)];
    }
  }

  f32x4 oA[8] = {}, oB[8] = {};
  float mA[4] = {-INFINITY, -INFINITY, -INFINITY, -INFINITY};
  float mB[4] = {-INFINITY, -INFINITY, -INFINITY, -INFINITY};
  float lA[4] = {0.f, 0.f, 0.f, 0.f}, lB[4] = {0.f, 0.f, 0.f, 0.f};

  auto stage = [&](int kt, int buf) {
#pragma unroll
    for (int c = 0; c < 4; ++c) {
      const int o2 = t * 16 + c * 4096;
      const int krow = o2 >> 8, kcb = o2 & 255;
      GLOAD_LDS16((const char*)Kg + hbase2 + (long)kt * 16384 + krow * 256 + (kcb ^ ((krow & 7) << 4)),
                  (char*)Ks[buf] + o2);
      const int vrow = o2 >> 7, vcb = o2 & 127;
      GLOAD_LDS16((const char*)Vt + (long)(bh * 128 + vrow) * T2 + (long)kt * 128 + (vcb ^ ((vrow & 7) << 4)),
                  (char*)Vs[buf] + o2);
    }
  };

  const int ntile = 2 * qt + 2;
  stage(0, 0);
  __syncthreads();

  for (int kt = 0; kt < ntile; ++kt) {
    const int cur = kt & 1;
    if (kt + 1 < ntile) stage(kt + 1, cur ^ 1);

    const char* KsB = (const char*)Ks[cur];
    const char* VsB = (const char*)Vs[cur];

    // per-strip body (verified math; exp2 domain)
    auto strip = [&](const bf16x8* qf, f32x4* o, float* m, float* lsum, int q0s) {
      f32x4 s[4] = {};
      __builtin_amdgcn_s_setprio(1);
#pragma unroll
      for (int tj = 0; tj < 4; ++tj)
#pragma unroll
        for (int ds = 0; ds < 4; ++ds) {
          bf16x8 kf = *(const bf16x8*)(KsB + (tj * 16 + lr) * 256 + ((ds * 64 + g16) ^ sw));
          s[tj] = __builtin_amdgcn_mfma_f32_16x16x32_bf16(qf[ds], kf, s[tj], 0, 0, 0);
        }
      __builtin_amdgcn_s_setprio(0);

      const bool diag = (kt == ((q0s + 15) >> 6));
      if (diag) {
#pragma unroll
        for (int tj = 0; tj < 4; ++tj)
#pragma unroll
          for (int j = 0; j < 4; ++j)
            if (kt * 64 + tj * 16 + lr > q0s + roff + j) s[tj][j] = -INFINITY;
      }

      float corr[4];
#pragma unroll
      for (int j = 0; j < 4; ++j) {
        float v = fmaxf(fmaxf(s[0][j], s[1][j]), fmaxf(s[2][j], s[3][j]));
        v = fmaxf(v, __shfl_xor(v, 1, 64));
        v = fmaxf(v, __shfl_xor(v, 2, 64));
        v = fmaxf(v, __shfl_xor(v, 4, 64));
        v = fmaxf(v, __shfl_xor(v, 8, 64));
        const float mn = fmaxf(m[j], v * C1);
        corr[j] = exp2f(m[j] - mn);
        m[j] = mn;
      }
      float rs[4] = {0.f, 0.f, 0.f, 0.f};
#pragma unroll
      for (int tj = 0; tj < 4; ++tj)
#pragma unroll
        for (int j = 0; j < 4; ++j) {
          const float p = exp2f(fmaf(s[tj][j], C1, -m[j]));
          rs[j] += p;
          const int prow = roff + j;
          *(unsigned short*)((char*)Ps[w] + prow * 128 + (((tj * 16 + lr) * 2) ^ ((prow & 7) << 4))) = f2b(p);
        }
#pragma unroll
      for (int j = 0; j < 4; ++j) {
        float v = rs[j];
        v += __shfl_xor(v, 1, 64);
        v += __shfl_xor(v, 2, 64);
        v += __shfl_xor(v, 4, 64);
        v += __shfl_xor(v, 8, 64);
        lsum[j] = lsum[j] * corr[j] + v;
      }
#pragma unroll
      for (int nj = 0; nj < 8; ++nj)
#pragma unroll
        for (int j = 0; j < 4; ++j) o[nj][j] *= corr[j];

      __builtin_amdgcn_s_setprio(1);
#pragma unroll
      for (int ks = 0; ks < 2; ++ks) {
        bf16x8 pf = *(const bf16x8*)((const char*)Ps[w] + lr * 128 + ((ks * 64 + g16) ^ sw));
#pragma unroll
        for (int nj = 0; nj < 8; ++nj) {
          bf16x8 vf = *(const bf16x8*)(VsB + (nj * 16 + lr) * 128 + ((ks * 64 + g16) ^ sw));
          o[nj] = __builtin_amdgcn_mfma_f32_16x16x32_bf16(pf, vf, o[nj], 0, 0, 0);
        }
      }
      __builtin_amdgcn_s_setprio(0);
    };

    if (kt <= 2 * qt) strip(qfA, oA, mA, lA, q0a);   // block-uniform skip of fully-masked tile
    strip(qfB, oB, mB, lB, q0b);

    __syncthreads();
  }

  const int b = bh >> 4, h = bh & 15;
  float invA[4], invB[4];
#pragma unroll
  for (int j = 0; j < 4; ++j) { invA[j] = 1.0f / lA[j]; invB[j] = 1.0f / lB[j]; }
#pragma unroll
  for (int nj = 0; nj < 8; ++nj)
#pragma unroll
    for (int j = 0; j < 4; ++j) {
      const int d = nj * 16 + lr;
      const int qa = q0a + roff + j;
      O[(long)(b * T + qa) * 2048 + h * 128 + d] = f2b(oA[nj][j] * invA[j]);
      const int qb = q0b + roff + j;
      O[(long)(b * T + qb) * 2048 + h * 128 + d] = f2b(oB[nj][j] * invB[j]);
    }
}

// ---------------- launch ----------------
extern "C" void kernel_launch(void* const* d_in, const int* in_sizes, int n_in,
                              void* d_out, int out_size, void* d_ws, size_t ws_size,
                              hipStream_t stream)
{
  const int B = 2, T = 2048, C = 2048;
  const int M = B * T;        // 4096
  const int N1 = 3 * C;       // 6144
  const float* x    = (const float*)d_in[0];
  const float* Wqkv = (const float*)d_in[1];
  const float* bqkv = (const float*)d_in[2];
  const float* Wout = (const float*)d_in[3];
  const float* bout = (const float*)d_in[4];
  float* out = (float*)d_out;

  char* p = (char*)d_ws;
  unsigned short* xb    = (unsigned short*)p; p += (size_t)M * C * 2;
  unsigned short* wqkvb = (unsigned short*)p; p += (size_t)N1 * C * 2;
  unsigned short* woutb = (unsigned short*)p; p += (size_t)C * C * 2;
  unsigned short* qkv   = (unsigned short*)p; p += (size_t)M * N1 * 2;
  unsigned short* Qr    = (unsigned short*)p; p += (size_t)M * C * 2;
  unsigned short* Kr    = (unsigned short*)p; p += (size_t)M * C * 2;
  unsigned short* Vt    = (unsigned short*)p; p += (size_t)M * C * 2;
  unsigned short* Ob    = xb;  // xb dead after QKV GEMM

  cast_kernel<<<M * C / 1024, 256, 0, stream>>>(x, xb, M * C);
  cast_kernel<<<N1 * C / 1024, 256, 0, stream>>>(Wqkv, wqkvb, N1 * C);
  cast_kernel<<<C * C / 1024, 256, 0, stream>>>(Wout, woutb, C * C);

  gemm256<0><<<dim3((M / 256) * (N1 / 256)), 512, 0, stream>>>(xb, wqkvb, bqkv, qkv, M, N1, C);

  rope_kernel<<<(32 * T * 64) / 256, 256, 0, stream>>>(qkv, Qr, Kr);
  vtrans_kernel<<<dim3(T / 64, 32), 256, 0, stream>>>(qkv, Vt);

  attn_fwd<<<dim3(32, T / 128), 256, 0, stream>>>(Qr, Kr, Vt, Ob, T);

  gemm256<1><<<dim3((M / 256) * (C / 256)), 512, 0, stream>>>(Ob, woutb, bout, out, M, C, C);
}

// Round 7
// 311.982 us; speedup vs baseline: 1.1879x; 1.1879x over previous
//
#include <hip/hip_runtime.h>
#include <hip/hip_bf16.h>

typedef __attribute__((ext_vector_type(8))) short bf16x8;
typedef __attribute__((ext_vector_type(4))) float f32x4;

#define GLOAD_LDS16(gptr, lptr) \
  __builtin_amdgcn_global_load_lds((const __attribute__((address_space(1))) void*)(gptr), \
                                   (__attribute__((address_space(3))) void*)(lptr), 16, 0, 0)

__device__ __forceinline__ unsigned short f2b(float f) {
  union { float f; unsigned u; } x; x.f = f;
  unsigned r = x.u + 0x7fffu + ((x.u >> 16) & 1u);
  return (unsigned short)(r >> 16);
}
__device__ __forceinline__ float b2f(unsigned short u) {
  union { unsigned u; float f; } x; x.u = ((unsigned)u) << 16;
  return x.f;
}

// ---------------- fp32 -> bf16 cast ----------------
__global__ void cast_kernel(const float* __restrict__ in, unsigned short* __restrict__ out, int n) {
  const int i = (blockIdx.x * 256 + threadIdx.x) * 4;
  if (i < n) {
    const float4 v = *(const float4*)(in + i);
    ushort4 r;
    r.x = f2b(v.x); r.y = f2b(v.y); r.z = f2b(v.z); r.w = f2b(v.w);
    *(ushort4*)(out + i) = r;
  }
}

// ---------------- GEMM 256x256, BK=64, read-ahead pipelined (core frozen at R4) ----------------
// Epilogue reordered: ni-inner so each output row's 4x32B stores issue contiguously (128B span).
template<int OUTF32>
__global__ __launch_bounds__(512, 2)
void gemm256(const unsigned short* __restrict__ A,
             const unsigned short* __restrict__ Bm,
             const float* __restrict__ bias,
             void* __restrict__ Cp,
             int M, int N, int K)
{
  __shared__ __align__(16) char Lds[131072];
  const int t  = threadIdx.x;
  const int l  = t & 63;
  const int w  = t >> 6;
  const int lr = l & 15;
  const int lkb = (l >> 4) << 4;
  const int wr = w >> 2;
  const int wc = w & 3;

  const int nwg = gridDim.x;
  const int wg  = (blockIdx.x & 7) * (nwg >> 3) + (blockIdx.x >> 3);
  const int NBN = N >> 8;
  const int bm = wg / NBN, bn = wg % NBN;

  const int sw3 = (lr & 7) << 4;
  const int ck0 = lkb ^ sw3;
  const int ck1 = (64 | lkb) ^ sw3;

  const int lb0 = t << 4;
  const int lb1 = lb0 + 8192;
  const int d0 = lb0 ^ (((lb0 >> 7) & 7) << 4);
  const int d1 = lb1 ^ (((lb1 >> 7) & 7) << 4);
  const long K2 = (long)K * 2;
  const char* Ab = (const char*)A  + (long)(bm * 256) * K2;
  const char* Bb = (const char*)Bm + (long)(bn * 256) * K2;
  const long s0 = (long)(d0 >> 7) * K2 + (d0 & 127);
  const long s1 = (long)(d1 >> 7) * K2 + (d1 & 127);
  const long hstep = (long)128 * K2;

  auto stageA = [&](int g, int h) {
    char* dst = Lds + (g & 1) * 65536 + h * 16384;
    const char* src = Ab + (long)h * hstep + (long)g * 128;
    GLOAD_LDS16(src + s0, dst + lb0);
    GLOAD_LDS16(src + s1, dst + lb1);
  };
  auto stageB = [&](int g, int h) {
    char* dst = Lds + (g & 1) * 65536 + 32768 + h * 16384;
    const char* src = Bb + (long)h * hstep + (long)g * 128;
    GLOAD_LDS16(src + s0, dst + lb0);
    GLOAD_LDS16(src + s1, dst + lb1);
  };

  f32x4 acc[8][4] = {};
  const int NT = K >> 6;
  const int brow = ((wc & 1) * 64 + lr) << 7;

  bf16x8 af[4][2], blo[2][2], bhi[2][2];

  stageA(0, 0); stageA(0, 1);
  stageB(0, 0); stageB(0, 1);
  stageB(1, 0); stageB(1, 1);
  asm volatile("s_waitcnt vmcnt(4)" ::: "memory");
  __builtin_amdgcn_s_barrier();
  {
    const char* AH0 = Lds + wr * 16384;
    const char* BH0 = Lds + 32768 + (wc >> 1) * 16384;
#pragma unroll
    for (int ni = 0; ni < 2; ++ni) {
      blo[ni][0] = *(const bf16x8*)(BH0 + brow + (ni << 11) + ck0);
      blo[ni][1] = *(const bf16x8*)(BH0 + brow + (ni << 11) + ck1);
    }
#pragma unroll
    for (int mi = 0; mi < 4; ++mi) {
      af[mi][0] = *(const bf16x8*)(AH0 + ((mi * 16 + lr) << 7) + ck0);
      af[mi][1] = *(const bf16x8*)(AH0 + ((mi * 16 + lr) << 7) + ck1);
    }
#pragma unroll
    for (int ni = 0; ni < 2; ++ni) {
      bhi[ni][0] = *(const bf16x8*)(BH0 + brow + ((ni + 2) << 11) + ck0);
      bhi[ni][1] = *(const bf16x8*)(BH0 + brow + ((ni + 2) << 11) + ck1);
    }
  }

  for (int tt = 0; tt < NT; ++tt) {
    const char* SB = Lds + (tt & 1) * 65536;
    const char* AH = SB + wr * 16384;

    if (tt + 1 < NT) { stageA(tt + 1, 0); stageA(tt + 1, 1); }
    __builtin_amdgcn_s_barrier();
    __builtin_amdgcn_sched_barrier(0);
    __builtin_amdgcn_s_setprio(1);
#pragma unroll
    for (int mi = 0; mi < 4; ++mi)
#pragma unroll
      for (int ni = 0; ni < 2; ++ni) {
        acc[mi][ni] = __builtin_amdgcn_mfma_f32_16x16x32_bf16(af[mi][0], blo[ni][0], acc[mi][ni], 0, 0, 0);
        acc[mi][ni] = __builtin_amdgcn_mfma_f32_16x16x32_bf16(af[mi][1], blo[ni][1], acc[mi][ni], 0, 0, 0);
      }
    __builtin_amdgcn_s_setprio(0);
    __builtin_amdgcn_s_barrier();
    __builtin_amdgcn_sched_barrier(0);

    __builtin_amdgcn_s_setprio(1);
#pragma unroll
    for (int mi = 0; mi < 4; ++mi)
#pragma unroll
      for (int ni = 0; ni < 2; ++ni) {
        acc[mi][ni + 2] = __builtin_amdgcn_mfma_f32_16x16x32_bf16(af[mi][0], bhi[ni][0], acc[mi][ni + 2], 0, 0, 0);
        acc[mi][ni + 2] = __builtin_amdgcn_mfma_f32_16x16x32_bf16(af[mi][1], bhi[ni][1], acc[mi][ni + 2], 0, 0, 0);
      }
    __builtin_amdgcn_s_setprio(0);
#pragma unroll
    for (int mi = 0; mi < 4; ++mi) {
      af[mi][0] = *(const bf16x8*)(AH + ((64 + mi * 16 + lr) << 7) + ck0);
      af[mi][1] = *(const bf16x8*)(AH + ((64 + mi * 16 + lr) << 7) + ck1);
    }
    __builtin_amdgcn_s_barrier();
    __builtin_amdgcn_sched_barrier(0);

    asm volatile("s_waitcnt vmcnt(0)" ::: "memory");
    if (tt + 2 < NT) stageB(tt + 2, 0);
    __builtin_amdgcn_s_setprio(1);
#pragma unroll
    for (int mi = 0; mi < 4; ++mi)
#pragma unroll
      for (int ni = 0; ni < 2; ++ni) {
        acc[mi + 4][ni] = __builtin_amdgcn_mfma_f32_16x16x32_bf16(af[mi][0], blo[ni][0], acc[mi + 4][ni], 0, 0, 0);
        acc[mi + 4][ni] = __builtin_amdgcn_mfma_f32_16x16x32_bf16(af[mi][1], blo[ni][1], acc[mi + 4][ni], 0, 0, 0);
      }
    __builtin_amdgcn_s_setprio(0);
    if (tt + 1 < NT) {
      const char* BHn = Lds + ((tt + 1) & 1) * 65536 + 32768 + (wc >> 1) * 16384;
#pragma unroll
      for (int ni = 0; ni < 2; ++ni) {
        blo[ni][0] = *(const bf16x8*)(BHn + brow + (ni << 11) + ck0);
        blo[ni][1] = *(const bf16x8*)(BHn + brow + (ni << 11) + ck1);
      }
    }
    __builtin_amdgcn_s_barrier();
    __builtin_amdgcn_sched_barrier(0);

    if (tt + 2 < NT) stageB(tt + 2, 1);
    __builtin_amdgcn_s_setprio(1);
#pragma unroll
    for (int mi = 0; mi < 4; ++mi)
#pragma unroll
      for (int ni = 0; ni < 2; ++ni) {
        acc[mi + 4][ni + 2] = __builtin_amdgcn_mfma_f32_16x16x32_bf16(af[mi][0], bhi[ni][0], acc[mi + 4][ni + 2], 0, 0, 0);
        acc[mi + 4][ni + 2] = __builtin_amdgcn_mfma_f32_16x16x32_bf16(af[mi][1], bhi[ni][1], acc[mi + 4][ni + 2], 0, 0, 0);
      }
    __builtin_amdgcn_s_setprio(0);
    if (tt + 1 < NT) {
      const char* SBn = Lds + ((tt + 1) & 1) * 65536;
      const char* AHn = SBn + wr * 16384;
      const char* BHn = SBn + 32768 + (wc >> 1) * 16384;
#pragma unroll
      for (int mi = 0; mi < 4; ++mi) {
        af[mi][0] = *(const bf16x8*)(AHn + ((mi * 16 + lr) << 7) + ck0);
        af[mi][1] = *(const bf16x8*)(AHn + ((mi * 16 + lr) << 7) + ck1);
      }
#pragma unroll
      for (int ni = 0; ni < 2; ++ni) {
        bhi[ni][0] = *(const bf16x8*)(BHn + brow + ((ni + 2) << 11) + ck0);
        bhi[ni][1] = *(const bf16x8*)(BHn + brow + ((ni + 2) << 11) + ck1);
      }
    }
    __builtin_amdgcn_s_barrier();
    __builtin_amdgcn_sched_barrier(0);
  }

  // epilogue: ni innermost -> 4x32B contiguous stores per row (full 128B span)
  const int roff = (l >> 4) << 2;
  const int row0 = bm * 256 + wr * 128 + roff;
  const int col0 = bn * 256 + wc * 64 + lr;
  float bv[4];
#pragma unroll
  for (int ni = 0; ni < 4; ++ni) bv[ni] = bias ? bias[col0 + ni * 16] : 0.0f;
#pragma unroll
  for (int mi = 0; mi < 8; ++mi) {
#pragma unroll
    for (int r = 0; r < 4; ++r) {
      const long rb = (long)(row0 + mi * 16 + r) * N;
#pragma unroll
      for (int ni = 0; ni < 4; ++ni) {
        const float v = acc[mi][ni][r] + bv[ni];
        if (OUTF32) ((float*)Cp)[rb + col0 + ni * 16] = v;
        else ((unsigned short*)Cp)[rb + col0 + ni * 16] = f2b(v);
      }
    }
  }
}

// ---------------- fused RoPE + V-transpose ----------------
// grid (T/64, B*H), 256 threads. RoPE: qkv -> Qr,Kr (B,H,T,D); V: qkv -> Vt (B,H,D,T).
__global__ void prep_kernel(const unsigned short* __restrict__ qkv,
                            unsigned short* __restrict__ Qr,
                            unsigned short* __restrict__ Kr,
                            unsigned short* __restrict__ Vt)
{
  const int T = 2048;
  __shared__ unsigned short ld[128][65];
  const int bh = blockIdx.y, tb = blockIdx.x;
  const int b = bh >> 4, h = bh & 15;
  const int t = threadIdx.x;

  // --- RoPE: 64 rows x 64 pairs = 16 items/thread ---
#pragma unroll
  for (int i = 0; i < 16; ++i) {
    const int idx = i * 256 + t;
    const int d  = idx & 63;
    const int tt = tb * 64 + (idx >> 6);
    const long base = ((long)(b * T + tt) * 3) * 2048 + h * 128;
    const float inv = exp2f(-(float)d * 0.2076205059304602f);
    const float fr = (float)tt * inv;
    float sn, cs;
    sincosf(fr, &sn, &cs);
    const float q1 = b2f(qkv[base + 2 * d]);
    const float q2 = b2f(qkv[base + 2 * d + 1]);
    const float k1 = b2f(qkv[base + 2048 + 2 * d]);
    const float k2 = b2f(qkv[base + 2048 + 2 * d + 1]);
    const long ob = ((long)bh * T + tt) * 128;
    Qr[ob + d]      = f2b(q1 * cs - q2 * sn);
    Qr[ob + 64 + d] = f2b(q1 * sn + q2 * cs);
    Kr[ob + d]      = f2b(k1 * cs - k2 * sn);
    Kr[ob + 64 + d] = f2b(k1 * sn + k2 * cs);
  }

  // --- V transpose via LDS ---
#pragma unroll
  for (int i = 0; i < 32; ++i) {
    const int idx = i * 256 + t;
    const int d = idx & 127, tr = idx >> 7;
    ld[d][tr] = qkv[((long)(b * T + tb * 64 + tr) * 3 + 2) * 2048 + h * 128 + d];
  }
  __syncthreads();
#pragma unroll
  for (int i = 0; i < 32; ++i) {
    const int idx = i * 256 + t;
    const int tc = idx & 63, dr = idx >> 6;
    Vt[((long)bh * 128 + dr) * T + tb * 64 + tc] = ld[dr][tc];
  }
}

// ---------------- causal flash attention (R4 structure, exp2 softmax) ----------------
// grid (B*H, T/64), qt reversed (heavy first); 4 waves x 16 q-rows; KV tile = 64.
// K/V double-buffered + prefetch; XOR-swizzled LDS (pre-swizzled global source).
__global__ __launch_bounds__(256)
void attn_fwd(const unsigned short* __restrict__ Q,
              const unsigned short* __restrict__ Kg,
              const unsigned short* __restrict__ Vt,
              unsigned short* __restrict__ O, int T)
{
  __shared__ __align__(16) unsigned short Ks[2][64 * 128];
  __shared__ __align__(16) unsigned short Vs[2][128 * 64];
  __shared__ __align__(16) unsigned short Ps[4][16 * 64];
  const int t = threadIdx.x;
  const int w = t >> 6, l = t & 63;
  const int lr = l & 15;
  const int g16 = (l >> 4) << 4;
  const int sw = (lr & 7) << 4;
  const int bh = blockIdx.x;
  const int qt = (gridDim.y - 1) - blockIdx.y;
  const int q0 = qt * 64 + w * 16;
  const long hbase = (long)bh * T * 128;
  const long hbase2 = hbase * 2;
  const long T2 = (long)T * 2;
  const int roff = (l >> 4) << 2;
  const float C1 = 0.08838834764831845f * 1.4426950408889634f;  // 1/sqrt(128)*log2(e)

  bf16x8 qf[4];
  const unsigned short* Qrow = Q + hbase + (long)(q0 + lr) * 128;
#pragma unroll
  for (int ds = 0; ds < 4; ++ds) qf[ds] = *(const bf16x8*)&Qrow[ds * 32 + (g16 >> 1)];

  f32x4 o[8] = {};
  float m[4]    = {-INFINITY, -INFINITY, -INFINITY, -INFINITY};
  float lsum[4] = {0.f, 0.f, 0.f, 0.f};

  auto stage = [&](int kt, int buf) {
#pragma unroll
    for (int c = 0; c < 4; ++c) {
      const int o2 = t * 16 + c * 4096;
      const int krow = o2 >> 8, kcb = o2 & 255;
      GLOAD_LDS16((const char*)Kg + hbase2 + (long)kt * 16384 + krow * 256 + (kcb ^ ((krow & 7) << 4)),
                  (char*)Ks[buf] + o2);
      const int vrow = o2 >> 7, vcb = o2 & 127;
      GLOAD_LDS16((const char*)Vt + (long)(bh * 128 + vrow) * T2 + (long)kt * 128 + (vcb ^ ((vrow & 7) << 4)),
                  (char*)Vs[buf] + o2);
    }
  };

  const int ntile = qt + 1;
  stage(0, 0);
  __syncthreads();

  for (int kt = 0; kt < ntile; ++kt) {
    const int cur = kt & 1;
    if (kt + 1 < ntile) stage(kt + 1, cur ^ 1);

    const char* KsB = (const char*)Ks[cur];
    const char* VsB = (const char*)Vs[cur];

    f32x4 s[4] = {};
    __builtin_amdgcn_s_setprio(1);
#pragma unroll
    for (int tj = 0; tj < 4; ++tj)
#pragma unroll
      for (int ds = 0; ds < 4; ++ds) {
        bf16x8 kf = *(const bf16x8*)(KsB + (tj * 16 + lr) * 256 + ((ds * 64 + g16) ^ sw));
        s[tj] = __builtin_amdgcn_mfma_f32_16x16x32_bf16(qf[ds], kf, s[tj], 0, 0, 0);
      }
    __builtin_amdgcn_s_setprio(0);

    if (kt == qt) {
#pragma unroll
      for (int tj = 0; tj < 4; ++tj)
#pragma unroll
        for (int j = 0; j < 4; ++j)
          if (kt * 64 + tj * 16 + lr > q0 + roff + j) s[tj][j] = -INFINITY;
    }

    float corr[4];
#pragma unroll
    for (int j = 0; j < 4; ++j) {
      float v = fmaxf(fmaxf(s[0][j], s[1][j]), fmaxf(s[2][j], s[3][j]));
      v = fmaxf(v, __shfl_xor(v, 1, 64));
      v = fmaxf(v, __shfl_xor(v, 2, 64));
      v = fmaxf(v, __shfl_xor(v, 4, 64));
      v = fmaxf(v, __shfl_xor(v, 8, 64));
      const float mn = fmaxf(m[j], v * C1);
      corr[j] = exp2f(m[j] - mn);
      m[j] = mn;
    }
    float rs[4] = {0.f, 0.f, 0.f, 0.f};
#pragma unroll
    for (int tj = 0; tj < 4; ++tj)
#pragma unroll
      for (int j = 0; j < 4; ++j) {
        const float p = exp2f(fmaf(s[tj][j], C1, -m[j]));
        rs[j] += p;
        const int prow = roff + j;
        *(unsigned short*)((char*)Ps[w] + prow * 128 + (((tj * 16 + lr) * 2) ^ ((prow & 7) << 4))) = f2b(p);
      }
#pragma unroll
    for (int j = 0; j < 4; ++j) {
      float v = rs[j];
      v += __shfl_xor(v, 1, 64);
      v += __shfl_xor(v, 2, 64);
      v += __shfl_xor(v, 4, 64);
      v += __shfl_xor(v, 8, 64);
      lsum[j] = lsum[j] * corr[j] + v;
    }
#pragma unroll
    for (int nj = 0; nj < 8; ++nj)
#pragma unroll
      for (int j = 0; j < 4; ++j) o[nj][j] *= corr[j];

    __builtin_amdgcn_s_setprio(1);
#pragma unroll
    for (int ks = 0; ks < 2; ++ks) {
      bf16x8 pf = *(const bf16x8*)((const char*)Ps[w] + lr * 128 + ((ks * 64 + g16) ^ sw));
#pragma unroll
      for (int nj = 0; nj < 8; ++nj) {
        bf16x8 vf = *(const bf16x8*)(VsB + (nj * 16 + lr) * 128 + ((ks * 64 + g16) ^ sw));
        o[nj] = __builtin_amdgcn_mfma_f32_16x16x32_bf16(pf, vf, o[nj], 0, 0, 0);
      }
    }
    __builtin_amdgcn_s_setprio(0);
    __syncthreads();
  }

  float inv[4];
#pragma unroll
  for (int j = 0; j < 4; ++j) inv[j] = 1.0f / lsum[j];
  const int b = bh >> 4, h = bh & 15;
#pragma unroll
  for (int nj = 0; nj < 8; ++nj)
#pragma unroll
    for (int j = 0; j < 4; ++j) {
      const int q = q0 + roff + j;
      const int d = nj * 16 + lr;
      O[(long)(b * T + q) * 2048 + h * 128 + d] = f2b(o[nj][j] * inv[j]);
    }
}

// ---------------- launch ----------------
extern "C" void kernel_launch(void* const* d_in, const int* in_sizes, int n_in,
                              void* d_out, int out_size, void* d_ws, size_t ws_size,
                              hipStream_t stream)
{
  const int B = 2, T = 2048, C = 2048;
  const int M = B * T;        // 4096
  const int N1 = 3 * C;       // 6144
  const float* x    = (const float*)d_in[0];
  const float* Wqkv = (const float*)d_in[1];
  const float* bqkv = (const float*)d_in[2];
  const float* Wout = (const float*)d_in[3];
  const float* bout = (const float*)d_in[4];
  float* out = (float*)d_out;

  char* p = (char*)d_ws;
  unsigned short* xb    = (unsigned short*)p; p += (size_t)M * C * 2;
  unsigned short* wqkvb = (unsigned short*)p; p += (size_t)N1 * C * 2;
  unsigned short* woutb = (unsigned short*)p; p += (size_t)C * C * 2;
  unsigned short* qkv   = (unsigned short*)p; p += (size_t)M * N1 * 2;
  unsigned short* Qr    = (unsigned short*)p; p += (size_t)M * C * 2;
  unsigned short* Kr    = (unsigned short*)p; p += (size_t)M * C * 2;
  unsigned short* Vt    = (unsigned short*)p; p += (size_t)M * C * 2;
  unsigned short* Ob    = xb;  // xb dead after QKV GEMM

  cast_kernel<<<M * C / 1024, 256, 0, stream>>>(x, xb, M * C);
  cast_kernel<<<N1 * C / 1024, 256, 0, stream>>>(Wqkv, wqkvb, N1 * C);
  cast_kernel<<<C * C / 1024, 256, 0, stream>>>(Wout, woutb, C * C);

  gemm256<0><<<dim3((M / 256) * (N1 / 256)), 512, 0, stream>>>(xb, wqkvb, bqkv, qkv, M, N1, C);

  prep_kernel<<<dim3(T / 64, 32), 256, 0, stream>>>(qkv, Qr, Kr, Vt);

  attn_fwd<<<dim3(32, T / 64), 256, 0, stream>>>(Qr, Kr, Vt, Ob, T);

  gemm256<1><<<dim3((M / 256) * (C / 256)), 512, 0, stream>>>(Ob, woutb, bout, out, M, C, C);
}

// Round 8
// 310.211 us; speedup vs baseline: 1.1947x; 1.0057x over previous
//
#include <hip/hip_runtime.h>
#include <hip/hip_bf16.h>

typedef __attribute__((ext_vector_type(8))) short bf16x8;
typedef __attribute__((ext_vector_type(4))) float f32x4;

#define GLOAD_LDS16(gptr, lptr) \
  __builtin_amdgcn_global_load_lds((const __attribute__((address_space(1))) void*)(gptr), \
                                   (__attribute__((address_space(3))) void*)(lptr), 16, 0, 0)

__device__ __forceinline__ unsigned short f2b(float f) {
  union { float f; unsigned u; } x; x.f = f;
  unsigned r = x.u + 0x7fffu + ((x.u >> 16) & 1u);
  return (unsigned short)(r >> 16);
}
__device__ __forceinline__ float b2f(unsigned short u) {
  union { unsigned u; float f; } x; x.u = ((unsigned)u) << 16;
  return x.f;
}

// ---------------- fp32 -> bf16 cast ----------------
__global__ void cast_kernel(const float* __restrict__ in, unsigned short* __restrict__ out, int n) {
  const int i = (blockIdx.x * 256 + threadIdx.x) * 4;
  if (i < n) {
    const float4 v = *(const float4*)(in + i);
    ushort4 r;
    r.x = f2b(v.x); r.y = f2b(v.y); r.z = f2b(v.z); r.w = f2b(v.w);
    *(ushort4*)(out + i) = r;
  }
}

// ---------------- GEMM 128x256, BK=64, read-ahead pipeline (R6 schedule, half BM) ----------------
// Grid-fill driven tile choice: QKV -> 768 blocks (3 even rounds), out -> 256 (1 round).
// 8 waves: 2M x 4N, wave tile 64x64, acc[4][4]. LDS 96KB: 2 slots x {A 16KB | B 32KB}.
// 4 phases/K-tile: P1 MFMA lo-lo (stage A t+1); P2 lo-hi (read af_hi);
// P3 vmcnt(0), hi-lo (stage B t+2 c01, read blo t+1); P4 hi-hi (stage B t+2 c23, read af/bhi t+1).
template<int OUTF32>
__global__ __launch_bounds__(512, 2)
void gemm128(const unsigned short* __restrict__ A,
             const unsigned short* __restrict__ Bm,
             const float* __restrict__ bias,
             void* __restrict__ Cp,
             int M, int N, int K)
{
  __shared__ __align__(16) char Lds[98304];   // 2 slots x 48KB
  const int t  = threadIdx.x;
  const int l  = t & 63;
  const int w  = t >> 6;
  const int lr = l & 15;
  const int lkb = (l >> 4) << 4;
  const int wr = w >> 2;        // 0-1: M half (64 rows)
  const int wc = w & 3;         // 0-3: N quarter (64 cols)

  const int nwg = gridDim.x;    // 768 or 256, both %8==0
  const int wg  = (blockIdx.x & 7) * (nwg >> 3) + (blockIdx.x >> 3);
  const int NBN = N >> 8;
  const int bm = wg / NBN, bn = wg % NBN;

  const int sw3 = (lr & 7) << 4;
  const int ck0 = lkb ^ sw3;
  const int ck1 = (64 | lkb) ^ sw3;

  const long K2 = (long)K * 2;
  const char* Ab = (const char*)A  + (long)(bm * 128) * K2;
  const char* Bb = (const char*)Bm + (long)(bn * 256) * K2;

  // pre-swizzled global source offsets for linear LDS dests (involution a^=((a>>7)&7)<<4)
  auto swzsrc = [&](int lo) -> long {
    const int d = lo ^ (((lo >> 7) & 7) << 4);
    return (long)(d >> 7) * K2 + (d & 127);
  };
  const int t16 = t << 4;
  const long a0 = swzsrc(t16),          a1 = swzsrc(t16 + 8192);
  const long b0 = a0,                   b1 = a1;          // same region offsets
  const long b2 = swzsrc(t16 + 16384),  b3 = swzsrc(t16 + 24576);

  auto stageA = [&](int g) {            // 16KB A-tile, 2 gloads/thread
    char* dst = Lds + (g & 1) * 49152 + t16;
    const char* src = Ab + (long)g * 128;
    GLOAD_LDS16(src + a0, dst);
    GLOAD_LDS16(src + a1, dst + 8192);
  };
  auto stageB2 = [&](int g, int half) { // 32KB B-tile in 2 halves of 16KB
    char* dst = Lds + (g & 1) * 49152 + 16384 + half * 16384 + t16;
    const char* src = Bb + (long)g * 128;
    GLOAD_LDS16(src + (half ? b2 : b0), dst);
    GLOAD_LDS16(src + (half ? b3 : b1), dst + 8192);
  };

  f32x4 acc[4][4] = {};
  const int NT = K >> 6;

  bf16x8 af[2][2], blo[2][2], bhi[2][2];

  // prologue: A(0), B(0), B(1); bootstrap tile-0 fragments
  stageA(0);
  stageB2(0, 0); stageB2(0, 1);
  stageB2(1, 0); stageB2(1, 1);
  asm volatile("s_waitcnt vmcnt(4)" ::: "memory");   // A(0)+B(0) landed
  __builtin_amdgcn_s_barrier();
  {
    const char* AH0 = Lds + wr * 8192;
    const char* BH0 = Lds + 16384 + wc * 8192;
#pragma unroll
    for (int ni = 0; ni < 2; ++ni) {
      blo[ni][0] = *(const bf16x8*)(BH0 + ((ni * 16 + lr) << 7) + ck0);
      blo[ni][1] = *(const bf16x8*)(BH0 + ((ni * 16 + lr) << 7) + ck1);
    }
#pragma unroll
    for (int mi = 0; mi < 2; ++mi) {
      af[mi][0] = *(const bf16x8*)(AH0 + ((mi * 16 + lr) << 7) + ck0);
      af[mi][1] = *(const bf16x8*)(AH0 + ((mi * 16 + lr) << 7) + ck1);
    }
#pragma unroll
    for (int ni = 0; ni < 2; ++ni) {
      bhi[ni][0] = *(const bf16x8*)(BH0 + (((ni + 2) * 16 + lr) << 7) + ck0);
      bhi[ni][1] = *(const bf16x8*)(BH0 + (((ni + 2) * 16 + lr) << 7) + ck1);
    }
  }

  for (int tt = 0; tt < NT; ++tt) {
    const char* SB = Lds + (tt & 1) * 49152;
    const char* AH = SB + wr * 8192;

    // ---- P1: stage A(t+1); MFMA lo x blo ----
    if (tt + 1 < NT) stageA(tt + 1);
    __builtin_amdgcn_s_barrier();
    __builtin_amdgcn_sched_barrier(0);
    __builtin_amdgcn_s_setprio(1);
#pragma unroll
    for (int mi = 0; mi < 2; ++mi)
#pragma unroll
      for (int ni = 0; ni < 2; ++ni) {
        acc[mi][ni] = __builtin_amdgcn_mfma_f32_16x16x32_bf16(af[mi][0], blo[ni][0], acc[mi][ni], 0, 0, 0);
        acc[mi][ni] = __builtin_amdgcn_mfma_f32_16x16x32_bf16(af[mi][1], blo[ni][1], acc[mi][ni], 0, 0, 0);
      }
    __builtin_amdgcn_s_setprio(0);
    __builtin_amdgcn_s_barrier();
    __builtin_amdgcn_sched_barrier(0);

    // ---- P2: MFMA lo x bhi; read af_hi(t) ----
    __builtin_amdgcn_s_setprio(1);
#pragma unroll
    for (int mi = 0; mi < 2; ++mi)
#pragma unroll
      for (int ni = 0; ni < 2; ++ni) {
        acc[mi][ni + 2] = __builtin_amdgcn_mfma_f32_16x16x32_bf16(af[mi][0], bhi[ni][0], acc[mi][ni + 2], 0, 0, 0);
        acc[mi][ni + 2] = __builtin_amdgcn_mfma_f32_16x16x32_bf16(af[mi][1], bhi[ni][1], acc[mi][ni + 2], 0, 0, 0);
      }
    __builtin_amdgcn_s_setprio(0);
#pragma unroll
    for (int mi = 0; mi < 2; ++mi) {
      af[mi][0] = *(const bf16x8*)(AH + (((mi + 2) * 16 + lr) << 7) + ck0);
      af[mi][1] = *(const bf16x8*)(AH + (((mi + 2) * 16 + lr) << 7) + ck1);
    }
    __builtin_amdgcn_s_barrier();
    __builtin_amdgcn_sched_barrier(0);

    // ---- P3: drain vmem; stage B(t+2) c01; MFMA hi x blo; read blo(t+1) ----
    asm volatile("s_waitcnt vmcnt(0)" ::: "memory");
    if (tt + 2 < NT) stageB2(tt + 2, 0);
    __builtin_amdgcn_s_setprio(1);
#pragma unroll
    for (int mi = 0; mi < 2; ++mi)
#pragma unroll
      for (int ni = 0; ni < 2; ++ni) {
        acc[mi + 2][ni] = __builtin_amdgcn_mfma_f32_16x16x32_bf16(af[mi][0], blo[ni][0], acc[mi + 2][ni], 0, 0, 0);
        acc[mi + 2][ni] = __builtin_amdgcn_mfma_f32_16x16x32_bf16(af[mi][1], blo[ni][1], acc[mi + 2][ni], 0, 0, 0);
      }
    __builtin_amdgcn_s_setprio(0);
    if (tt + 1 < NT) {
      const char* BHn = Lds + ((tt + 1) & 1) * 49152 + 16384 + wc * 8192;
#pragma unroll
      for (int ni = 0; ni < 2; ++ni) {
        blo[ni][0] = *(const bf16x8*)(BHn + ((ni * 16 + lr) << 7) + ck0);
        blo[ni][1] = *(const bf16x8*)(BHn + ((ni * 16 + lr) << 7) + ck1);
      }
    }
    __builtin_amdgcn_s_barrier();
    __builtin_amdgcn_sched_barrier(0);

    // ---- P4: stage B(t+2) c23; MFMA hi x bhi; read af_lo(t+1), bhi(t+1) ----
    if (tt + 2 < NT) stageB2(tt + 2, 1);
    __builtin_amdgcn_s_setprio(1);
#pragma unroll
    for (int mi = 0; mi < 2; ++mi)
#pragma unroll
      for (int ni = 0; ni < 2; ++ni) {
        acc[mi + 2][ni + 2] = __builtin_amdgcn_mfma_f32_16x16x32_bf16(af[mi][0], bhi[ni][0], acc[mi + 2][ni + 2], 0, 0, 0);
        acc[mi + 2][ni + 2] = __builtin_amdgcn_mfma_f32_16x16x32_bf16(af[mi][1], bhi[ni][1], acc[mi + 2][ni + 2], 0, 0, 0);
      }
    __builtin_amdgcn_s_setprio(0);
    if (tt + 1 < NT) {
      const char* SBn = Lds + ((tt + 1) & 1) * 49152;
      const char* AHn = SBn + wr * 8192;
      const char* BHn = SBn + 16384 + wc * 8192;
#pragma unroll
      for (int mi = 0; mi < 2; ++mi) {
        af[mi][0] = *(const bf16x8*)(AHn + ((mi * 16 + lr) << 7) + ck0);
        af[mi][1] = *(const bf16x8*)(AHn + ((mi * 16 + lr) << 7) + ck1);
      }
#pragma unroll
      for (int ni = 0; ni < 2; ++ni) {
        bhi[ni][0] = *(const bf16x8*)(BHn + (((ni + 2) * 16 + lr) << 7) + ck0);
        bhi[ni][1] = *(const bf16x8*)(BHn + (((ni + 2) * 16 + lr) << 7) + ck1);
      }
    }
    __builtin_amdgcn_s_barrier();
    __builtin_amdgcn_sched_barrier(0);
  }

  // epilogue: ni innermost -> contiguous 4x32B stores per row
  const int roff = (l >> 4) << 2;
  const int row0 = bm * 128 + wr * 64 + roff;
  const int col0 = bn * 256 + wc * 64 + lr;
  float bv[4];
#pragma unroll
  for (int ni = 0; ni < 4; ++ni) bv[ni] = bias ? bias[col0 + ni * 16] : 0.0f;
#pragma unroll
  for (int mi = 0; mi < 4; ++mi) {
#pragma unroll
    for (int r = 0; r < 4; ++r) {
      const long rb = (long)(row0 + mi * 16 + r) * N;
#pragma unroll
      for (int ni = 0; ni < 4; ++ni) {
        const float v = acc[mi][ni][r] + bv[ni];
        if (OUTF32) ((float*)Cp)[rb + col0 + ni * 16] = v;
        else ((unsigned short*)Cp)[rb + col0 + ni * 16] = f2b(v);
      }
    }
  }
}

// ---------------- fused RoPE + V-transpose ----------------
__global__ void prep_kernel(const unsigned short* __restrict__ qkv,
                            unsigned short* __restrict__ Qr,
                            unsigned short* __restrict__ Kr,
                            unsigned short* __restrict__ Vt)
{
  const int T = 2048;
  __shared__ unsigned short ld[128][65];
  const int bh = blockIdx.y, tb = blockIdx.x;
  const int b = bh >> 4, h = bh & 15;
  const int t = threadIdx.x;

#pragma unroll
  for (int i = 0; i < 16; ++i) {
    const int idx = i * 256 + t;
    const int d  = idx & 63;
    const int tt = tb * 64 + (idx >> 6);
    const long base = ((long)(b * T + tt) * 3) * 2048 + h * 128;
    const float inv = exp2f(-(float)d * 0.2076205059304602f);
    const float fr = (float)tt * inv;
    float sn, cs;
    sincosf(fr, &sn, &cs);
    const float q1 = b2f(qkv[base + 2 * d]);
    const float q2 = b2f(qkv[base + 2 * d + 1]);
    const float k1 = b2f(qkv[base + 2048 + 2 * d]);
    const float k2 = b2f(qkv[base + 2048 + 2 * d + 1]);
    const long ob = ((long)bh * T + tt) * 128;
    Qr[ob + d]      = f2b(q1 * cs - q2 * sn);
    Qr[ob + 64 + d] = f2b(q1 * sn + q2 * cs);
    Kr[ob + d]      = f2b(k1 * cs - k2 * sn);
    Kr[ob + 64 + d] = f2b(k1 * sn + k2 * cs);
  }

#pragma unroll
  for (int i = 0; i < 32; ++i) {
    const int idx = i * 256 + t;
    const int d = idx & 127, tr = idx >> 7;
    ld[d][tr] = qkv[((long)(b * T + tb * 64 + tr) * 3 + 2) * 2048 + h * 128 + d];
  }
  __syncthreads();
#pragma unroll
  for (int i = 0; i < 32; ++i) {
    const int idx = i * 256 + t;
    const int tc = idx & 63, dr = idx >> 6;
    Vt[((long)bh * 128 + dr) * T + tb * 64 + tc] = ld[dr][tc];
  }
}

// ---------------- causal flash attention (R4 structure, exp2 softmax) ----------------
__global__ __launch_bounds__(256)
void attn_fwd(const unsigned short* __restrict__ Q,
              const unsigned short* __restrict__ Kg,
              const unsigned short* __restrict__ Vt,
              unsigned short* __restrict__ O, int T)
{
  __shared__ __align__(16) unsigned short Ks[2][64 * 128];
  __shared__ __align__(16) unsigned short Vs[2][128 * 64];
  __shared__ __align__(16) unsigned short Ps[4][16 * 64];
  const int t = threadIdx.x;
  const int w = t >> 6, l = t & 63;
  const int lr = l & 15;
  const int g16 = (l >> 4) << 4;
  const int sw = (lr & 7) << 4;
  const int bh = blockIdx.x;
  const int qt = (gridDim.y - 1) - blockIdx.y;
  const int q0 = qt * 64 + w * 16;
  const long hbase = (long)bh * T * 128;
  const long hbase2 = hbase * 2;
  const long T2 = (long)T * 2;
  const int roff = (l >> 4) << 2;
  const float C1 = 0.08838834764831845f * 1.4426950408889634f;

  bf16x8 qf[4];
  const unsigned short* Qrow = Q + hbase + (long)(q0 + lr) * 128;
#pragma unroll
  for (int ds = 0; ds < 4; ++ds) qf[ds] = *(const bf16x8*)&Qrow[ds * 32 + (g16 >> 1)];

  f32x4 o[8] = {};
  float m[4]    = {-INFINITY, -INFINITY, -INFINITY, -INFINITY};
  float lsum[4] = {0.f, 0.f, 0.f, 0.f};

  auto stage = [&](int kt, int buf) {
#pragma unroll
    for (int c = 0; c < 4; ++c) {
      const int o2 = t * 16 + c * 4096;
      const int krow = o2 >> 8, kcb = o2 & 255;
      GLOAD_LDS16((const char*)Kg + hbase2 + (long)kt * 16384 + krow * 256 + (kcb ^ ((krow & 7) << 4)),
                  (char*)Ks[buf] + o2);
      const int vrow = o2 >> 7, vcb = o2 & 127;
      GLOAD_LDS16((const char*)Vt + (long)(bh * 128 + vrow) * T2 + (long)kt * 128 + (vcb ^ ((vrow & 7) << 4)),
                  (char*)Vs[buf] + o2);
    }
  };

  const int ntile = qt + 1;
  stage(0, 0);
  __syncthreads();

  for (int kt = 0; kt < ntile; ++kt) {
    const int cur = kt & 1;
    if (kt + 1 < ntile) stage(kt + 1, cur ^ 1);

    const char* KsB = (const char*)Ks[cur];
    const char* VsB = (const char*)Vs[cur];

    f32x4 s[4] = {};
    __builtin_amdgcn_s_setprio(1);
#pragma unroll
    for (int tj = 0; tj < 4; ++tj)
#pragma unroll
      for (int ds = 0; ds < 4; ++ds) {
        bf16x8 kf = *(const bf16x8*)(KsB + (tj * 16 + lr) * 256 + ((ds * 64 + g16) ^ sw));
        s[tj] = __builtin_amdgcn_mfma_f32_16x16x32_bf16(qf[ds], kf, s[tj], 0, 0, 0);
      }
    __builtin_amdgcn_s_setprio(0);

    if (kt == qt) {
#pragma unroll
      for (int tj = 0; tj < 4; ++tj)
#pragma unroll
        for (int j = 0; j < 4; ++j)
          if (kt * 64 + tj * 16 + lr > q0 + roff + j) s[tj][j] = -INFINITY;
    }

    float corr[4];
#pragma unroll
    for (int j = 0; j < 4; ++j) {
      float v = fmaxf(fmaxf(s[0][j], s[1][j]), fmaxf(s[2][j], s[3][j]));
      v = fmaxf(v, __shfl_xor(v, 1, 64));
      v = fmaxf(v, __shfl_xor(v, 2, 64));
      v = fmaxf(v, __shfl_xor(v, 4, 64));
      v = fmaxf(v, __shfl_xor(v, 8, 64));
      const float mn = fmaxf(m[j], v * C1);
      corr[j] = exp2f(m[j] - mn);
      m[j] = mn;
    }
    float rs[4] = {0.f, 0.f, 0.f, 0.f};
#pragma unroll
    for (int tj = 0; tj < 4; ++tj)
#pragma unroll
      for (int j = 0; j < 4; ++j) {
        const float p = exp2f(fmaf(s[tj][j], C1, -m[j]));
        rs[j] += p;
        const int prow = roff + j;
        *(unsigned short*)((char*)Ps[w] + prow * 128 + (((tj * 16 + lr) * 2) ^ ((prow & 7) << 4))) = f2b(p);
      }
#pragma unroll
    for (int j = 0; j < 4; ++j) {
      float v = rs[j];
      v += __shfl_xor(v, 1, 64);
      v += __shfl_xor(v, 2, 64);
      v += __shfl_xor(v, 4, 64);
      v += __shfl_xor(v, 8, 64);
      lsum[j] = lsum[j] * corr[j] + v;
    }
#pragma unroll
    for (int nj = 0; nj < 8; ++nj)
#pragma unroll
      for (int j = 0; j < 4; ++j) o[nj][j] *= corr[j];

    __builtin_amdgcn_s_setprio(1);
#pragma unroll
    for (int ks = 0; ks < 2; ++ks) {
      bf16x8 pf = *(const bf16x8*)((const char*)Ps[w] + lr * 128 + ((ks * 64 + g16) ^ sw));
#pragma unroll
      for (int nj = 0; nj < 8; ++nj) {
        bf16x8 vf = *(const bf16x8*)(VsB + (nj * 16 + lr) * 128 + ((ks * 64 + g16) ^ sw));
        o[nj] = __builtin_amdgcn_mfma_f32_16x16x32_bf16(pf, vf, o[nj], 0, 0, 0);
      }
    }
    __builtin_amdgcn_s_setprio(0);
    __syncthreads();
  }

  float inv[4];
#pragma unroll
  for (int j = 0; j < 4; ++j) inv[j] = 1.0f / lsum[j];
  const int b = bh >> 4, h = bh & 15;
#pragma unroll
  for (int nj = 0; nj < 8; ++nj)
#pragma unroll
    for (int j = 0; j < 4; ++j) {
      const int q = q0 + roff + j;
      const int d = nj * 16 + lr;
      O[(long)(b * T + q) * 2048 + h * 128 + d] = f2b(o[nj][j] * inv[j]);
    }
}

// ---------------- launch ----------------
extern "C" void kernel_launch(void* const* d_in, const int* in_sizes, int n_in,
                              void* d_out, int out_size, void* d_ws, size_t ws_size,
                              hipStream_t stream)
{
  const int B = 2, T = 2048, C = 2048;
  const int M = B * T;        // 4096
  const int N1 = 3 * C;       // 6144
  const float* x    = (const float*)d_in[0];
  const float* Wqkv = (const float*)d_in[1];
  const float* bqkv = (const float*)d_in[2];
  const float* Wout = (const float*)d_in[3];
  const float* bout = (const float*)d_in[4];
  float* out = (float*)d_out;

  char* p = (char*)d_ws;
  unsigned short* xb    = (unsigned short*)p; p += (size_t)M * C * 2;
  unsigned short* wqkvb = (unsigned short*)p; p += (size_t)N1 * C * 2;
  unsigned short* woutb = (unsigned short*)p; p += (size_t)C * C * 2;
  unsigned short* qkv   = (unsigned short*)p; p += (size_t)M * N1 * 2;
  unsigned short* Qr    = (unsigned short*)p; p += (size_t)M * C * 2;
  unsigned short* Kr    = (unsigned short*)p; p += (size_t)M * C * 2;
  unsigned short* Vt    = (unsigned short*)p; p += (size_t)M * C * 2;
  unsigned short* Ob    = xb;  // xb dead after QKV GEMM

  cast_kernel<<<M * C / 1024, 256, 0, stream>>>(x, xb, M * C);
  cast_kernel<<<N1 * C / 1024, 256, 0, stream>>>(Wqkv, wqkvb, N1 * C);
  cast_kernel<<<C * C / 1024, 256, 0, stream>>>(Wout, woutb, C * C);

  gemm128<0><<<dim3((M / 128) * (N1 / 256)), 512, 0, stream>>>(xb, wqkvb, bqkv, qkv, M, N1, C);

  prep_kernel<<<dim3(T / 64, 32), 256, 0, stream>>>(qkv, Qr, Kr, Vt);

  attn_fwd<<<dim3(32, T / 64), 256, 0, stream>>>(Qr, Kr, Vt, Ob, T);

  gemm128<1><<<dim3((M / 128) * (C / 256)), 512, 0, stream>>>(Ob, woutb, bout, out, M, C, C);
}

// Round 9
// 307.519 us; speedup vs baseline: 1.2052x; 1.0088x over previous
//
#include <hip/hip_runtime.h>
#include <hip/hip_bf16.h>

typedef __attribute__((ext_vector_type(8))) short bf16x8;
typedef __attribute__((ext_vector_type(4))) float f32x4;

#define GLOAD_LDS16(gptr, lptr) \
  __builtin_amdgcn_global_load_lds((const __attribute__((address_space(1))) void*)(gptr), \
                                   (__attribute__((address_space(3))) void*)(lptr), 16, 0, 0)

__device__ __forceinline__ unsigned short f2b(float f) {
  union { float f; unsigned u; } x; x.f = f;
  unsigned r = x.u + 0x7fffu + ((x.u >> 16) & 1u);
  return (unsigned short)(r >> 16);
}
__device__ __forceinline__ float b2f(unsigned short u) {
  union { unsigned u; float f; } x; x.u = ((unsigned)u) << 16;
  return x.f;
}

// ---------------- fp32 -> bf16 cast ----------------
__global__ void cast_kernel(const float* __restrict__ in, unsigned short* __restrict__ out, int n) {
  const int i = (blockIdx.x * 256 + threadIdx.x) * 4;
  if (i < n) {
    const float4 v = *(const float4*)(in + i);
    ushort4 r;
    r.x = f2b(v.x); r.y = f2b(v.y); r.z = f2b(v.z); r.w = f2b(v.w);
    *(ushort4*)(out + i) = r;
  }
}

// ---------------- GEMM 128x256, BK=32, 3-slot LDS, 2 blocks/CU ----------------
// Occupancy-first redesign: LDS 72KB (3 x 24KB slots) -> 2 blocks/CU; cross-block
// wave overlap (m114) hides barrier/wait stalls. One barrier + one counted
// vmcnt(3) per K-tile; frags read-ahead; stage(t+2) gives ~2 phases of HBM flight.
// Swizzle (BK=32, 64B rows): a ^= ((a>>7)&3)<<4 (involution; 2-way bank alias = free),
// applied to stage-source and read side identically.
template<int OUTF32>
__global__ __launch_bounds__(512, 4)
void gemm128(const unsigned short* __restrict__ A,
             const unsigned short* __restrict__ Bm,
             const float* __restrict__ bias,
             void* __restrict__ Cp,
             int M, int N, int K)
{
  __shared__ __align__(16) char Lds[73728];   // 3 slots x (A 8KB | B 16KB)
  const int t  = threadIdx.x;
  const int l  = t & 63;
  const int w  = t >> 6;
  const int lr = l & 15;
  const int lkb = (l >> 4) << 4;   // 0/16/32/48 within 64B row
  const int wr = w >> 2;           // 0-1: M half
  const int wc = w & 3;            // 0-3: N quarter

  const int nwg = gridDim.x;       // 768 / 256, both %8==0
  const int wg  = (blockIdx.x & 7) * (nwg >> 3) + (blockIdx.x >> 3);
  const int NBN = N >> 8;
  const int bm = wg / NBN, bn = wg % NBN;

  const long K2 = (long)K * 2;
  const char* Ab = (const char*)A  + (long)(bm * 128) * K2;
  const char* Bb = (const char*)Bm + (long)(bn * 256) * K2;

  auto swz = [](int a) -> int { return a ^ (((a >> 7) & 3) << 4); };

  // staging sources: LDS linear loc x holds global elem swz(x) (region-local)
  const int t16 = t << 4;
  const int da  = swz(t16);
  const long sa = (long)(da >> 6) * K2 + (da & 63);
  const int db0 = swz(t16), db1 = swz(8192 + t16);
  const long sb0 = (long)(db0 >> 6) * K2 + (db0 & 63);
  const long sb1 = (long)(db1 >> 6) * K2 + (db1 & 63);

  auto stage = [&](int g) {        // 3 gloads: A 8KB, B 16KB (2 halves)
    char* S = Lds + (g % 3) * 24576;
    const char* As = Ab + (long)g * 64;
    const char* Bs = Bb + (long)g * 64;
    GLOAD_LDS16(As + sa,  S + t16);
    GLOAD_LDS16(Bs + sb0, S + 8192 + t16);
    GLOAD_LDS16(Bs + sb1, S + 16384 + t16);
  };

  // read offsets (swizzled), region-local + region base
  int aoff[4], boff[4];
#pragma unroll
  for (int mi = 0; mi < 4; ++mi) {
    const int a = ((wr * 64 + mi * 16 + lr) << 6) | lkb;
    aoff[mi] = swz(a);
  }
#pragma unroll
  for (int ni = 0; ni < 4; ++ni) {
    const int a = ((wc * 64 + ni * 16 + lr) << 6) | lkb;
    boff[ni] = 8192 + swz(a);
  }

  f32x4 acc[4][4] = {};
  const int NT = K >> 5;
  bf16x8 af[4], bfr[4];

  // prologue: stage 0,1; wait tile0; read frags(0)
  stage(0); stage(1);
  asm volatile("s_waitcnt vmcnt(3)" ::: "memory");
  __builtin_amdgcn_s_barrier();
  __builtin_amdgcn_sched_barrier(0);
#pragma unroll
  for (int mi = 0; mi < 4; ++mi) af[mi]  = *(const bf16x8*)(Lds + aoff[mi]);
#pragma unroll
  for (int ni = 0; ni < 4; ++ni) bfr[ni] = *(const bf16x8*)(Lds + boff[ni]);

  for (int tt = 0; tt < NT; ++tt) {
    if (tt + 2 < NT) stage(tt + 2);
    __builtin_amdgcn_s_setprio(1);
#pragma unroll
    for (int mi = 0; mi < 4; ++mi)
#pragma unroll
      for (int ni = 0; ni < 4; ++ni)
        acc[mi][ni] = __builtin_amdgcn_mfma_f32_16x16x32_bf16(af[mi], bfr[ni], acc[mi][ni], 0, 0, 0);
    __builtin_amdgcn_s_setprio(0);
    if (tt + 1 < NT) {
      if (tt + 2 < NT) asm volatile("s_waitcnt vmcnt(3)" ::: "memory");
      else             asm volatile("s_waitcnt vmcnt(0)" ::: "memory");
      __builtin_amdgcn_s_barrier();
      __builtin_amdgcn_sched_barrier(0);
      const char* S = Lds + ((tt + 1) % 3) * 24576;
#pragma unroll
      for (int mi = 0; mi < 4; ++mi) af[mi]  = *(const bf16x8*)(S + aoff[mi]);
#pragma unroll
      for (int ni = 0; ni < 4; ++ni) bfr[ni] = *(const bf16x8*)(S + boff[ni]);
    }
  }

  // epilogue: ni innermost -> contiguous 4x32B stores per row
  const int roff = (l >> 4) << 2;
  const int row0 = bm * 128 + wr * 64 + roff;
  const int col0 = bn * 256 + wc * 64 + lr;
  float bv[4];
#pragma unroll
  for (int ni = 0; ni < 4; ++ni) bv[ni] = bias ? bias[col0 + ni * 16] : 0.0f;
#pragma unroll
  for (int mi = 0; mi < 4; ++mi) {
#pragma unroll
    for (int r = 0; r < 4; ++r) {
      const long rb = (long)(row0 + mi * 16 + r) * N;
#pragma unroll
      for (int ni = 0; ni < 4; ++ni) {
        const float v = acc[mi][ni][r] + bv[ni];
        if (OUTF32) ((float*)Cp)[rb + col0 + ni * 16] = v;
        else ((unsigned short*)Cp)[rb + col0 + ni * 16] = f2b(v);
      }
    }
  }
}

// ---------------- fused RoPE + V-transpose ----------------
__global__ void prep_kernel(const unsigned short* __restrict__ qkv,
                            unsigned short* __restrict__ Qr,
                            unsigned short* __restrict__ Kr,
                            unsigned short* __restrict__ Vt)
{
  const int T = 2048;
  __shared__ unsigned short ld[128][65];
  const int bh = blockIdx.y, tb = blockIdx.x;
  const int b = bh >> 4, h = bh & 15;
  const int t = threadIdx.x;

#pragma unroll
  for (int i = 0; i < 16; ++i) {
    const int idx = i * 256 + t;
    const int d  = idx & 63;
    const int tt = tb * 64 + (idx >> 6);
    const long base = ((long)(b * T + tt) * 3) * 2048 + h * 128;
    const float inv = exp2f(-(float)d * 0.2076205059304602f);
    const float fr = (float)tt * inv;
    float sn, cs;
    sincosf(fr, &sn, &cs);
    const float q1 = b2f(qkv[base + 2 * d]);
    const float q2 = b2f(qkv[base + 2 * d + 1]);
    const float k1 = b2f(qkv[base + 2048 + 2 * d]);
    const float k2 = b2f(qkv[base + 2048 + 2 * d + 1]);
    const long ob = ((long)bh * T + tt) * 128;
    Qr[ob + d]      = f2b(q1 * cs - q2 * sn);
    Qr[ob + 64 + d] = f2b(q1 * sn + q2 * cs);
    Kr[ob + d]      = f2b(k1 * cs - k2 * sn);
    Kr[ob + 64 + d] = f2b(k1 * sn + k2 * cs);
  }

#pragma unroll
  for (int i = 0; i < 32; ++i) {
    const int idx = i * 256 + t;
    const int d = idx & 127, tr = idx >> 7;
    ld[d][tr] = qkv[((long)(b * T + tb * 64 + tr) * 3 + 2) * 2048 + h * 128 + d];
  }
  __syncthreads();
#pragma unroll
  for (int i = 0; i < 32; ++i) {
    const int idx = i * 256 + t;
    const int tc = idx & 63, dr = idx >> 6;
    Vt[((long)bh * 128 + dr) * T + tb * 64 + tc] = ld[dr][tc];
  }
}

// ---------------- causal flash attention (R4 structure, exp2 softmax) ----------------
__global__ __launch_bounds__(256)
void attn_fwd(const unsigned short* __restrict__ Q,
              const unsigned short* __restrict__ Kg,
              const unsigned short* __restrict__ Vt,
              unsigned short* __restrict__ O, int T)
{
  __shared__ __align__(16) unsigned short Ks[2][64 * 128];
  __shared__ __align__(16) unsigned short Vs[2][128 * 64];
  __shared__ __align__(16) unsigned short Ps[4][16 * 64];
  const int t = threadIdx.x;
  const int w = t >> 6, l = t & 63;
  const int lr = l & 15;
  const int g16 = (l >> 4) << 4;
  const int sw = (lr & 7) << 4;
  const int bh = blockIdx.x;
  const int qt = (gridDim.y - 1) - blockIdx.y;
  const int q0 = qt * 64 + w * 16;
  const long hbase = (long)bh * T * 128;
  const long hbase2 = hbase * 2;
  const long T2 = (long)T * 2;
  const int roff = (l >> 4) << 2;
  const float C1 = 0.08838834764831845f * 1.4426950408889634f;

  bf16x8 qf[4];
  const unsigned short* Qrow = Q + hbase + (long)(q0 + lr) * 128;
#pragma unroll
  for (int ds = 0; ds < 4; ++ds) qf[ds] = *(const bf16x8*)&Qrow[ds * 32 + (g16 >> 1)];

  f32x4 o[8] = {};
  float m[4]    = {-INFINITY, -INFINITY, -INFINITY, -INFINITY};
  float lsum[4] = {0.f, 0.f, 0.f, 0.f};

  auto stage = [&](int kt, int buf) {
#pragma unroll
    for (int c = 0; c < 4; ++c) {
      const int o2 = t * 16 + c * 4096;
      const int krow = o2 >> 8, kcb = o2 & 255;
      GLOAD_LDS16((const char*)Kg + hbase2 + (long)kt * 16384 + krow * 256 + (kcb ^ ((krow & 7) << 4)),
                  (char*)Ks[buf] + o2);
      const int vrow = o2 >> 7, vcb = o2 & 127;
      GLOAD_LDS16((const char*)Vt + (long)(bh * 128 + vrow) * T2 + (long)kt * 128 + (vcb ^ ((vrow & 7) << 4)),
                  (char*)Vs[buf] + o2);
    }
  };

  const int ntile = qt + 1;
  stage(0, 0);
  __syncthreads();

  for (int kt = 0; kt < ntile; ++kt) {
    const int cur = kt & 1;
    if (kt + 1 < ntile) stage(kt + 1, cur ^ 1);

    const char* KsB = (const char*)Ks[cur];
    const char* VsB = (const char*)Vs[cur];

    f32x4 s[4] = {};
    __builtin_amdgcn_s_setprio(1);
#pragma unroll
    for (int tj = 0; tj < 4; ++tj)
#pragma unroll
      for (int ds = 0; ds < 4; ++ds) {
        bf16x8 kf = *(const bf16x8*)(KsB + (tj * 16 + lr) * 256 + ((ds * 64 + g16) ^ sw));
        s[tj] = __builtin_amdgcn_mfma_f32_16x16x32_bf16(qf[ds], kf, s[tj], 0, 0, 0);
      }
    __builtin_amdgcn_s_setprio(0);

    if (kt == qt) {
#pragma unroll
      for (int tj = 0; tj < 4; ++tj)
#pragma unroll
        for (int j = 0; j < 4; ++j)
          if (kt * 64 + tj * 16 + lr > q0 + roff + j) s[tj][j] = -INFINITY;
    }

    float corr[4];
#pragma unroll
    for (int j = 0; j < 4; ++j) {
      float v = fmaxf(fmaxf(s[0][j], s[1][j]), fmaxf(s[2][j], s[3][j]));
      v = fmaxf(v, __shfl_xor(v, 1, 64));
      v = fmaxf(v, __shfl_xor(v, 2, 64));
      v = fmaxf(v, __shfl_xor(v, 4, 64));
      v = fmaxf(v, __shfl_xor(v, 8, 64));
      const float mn = fmaxf(m[j], v * C1);
      corr[j] = exp2f(m[j] - mn);
      m[j] = mn;
    }
    float rs[4] = {0.f, 0.f, 0.f, 0.f};
#pragma unroll
    for (int tj = 0; tj < 4; ++tj)
#pragma unroll
      for (int j = 0; j < 4; ++j) {
        const float p = exp2f(fmaf(s[tj][j], C1, -m[j]));
        rs[j] += p;
        const int prow = roff + j;
        *(unsigned short*)((char*)Ps[w] + prow * 128 + (((tj * 16 + lr) * 2) ^ ((prow & 7) << 4))) = f2b(p);
      }
#pragma unroll
    for (int j = 0; j < 4; ++j) {
      float v = rs[j];
      v += __shfl_xor(v, 1, 64);
      v += __shfl_xor(v, 2, 64);
      v += __shfl_xor(v, 4, 64);
      v += __shfl_xor(v, 8, 64);
      lsum[j] = lsum[j] * corr[j] + v;
    }
#pragma unroll
    for (int nj = 0; nj < 8; ++nj)
#pragma unroll
      for (int j = 0; j < 4; ++j) o[nj][j] *= corr[j];

    __builtin_amdgcn_s_setprio(1);
#pragma unroll
    for (int ks = 0; ks < 2; ++ks) {
      bf16x8 pf = *(const bf16x8*)((const char*)Ps[w] + lr * 128 + ((ks * 64 + g16) ^ sw));
#pragma unroll
      for (int nj = 0; nj < 8; ++nj) {
        bf16x8 vf = *(const bf16x8*)(VsB + (nj * 16 + lr) * 128 + ((ks * 64 + g16) ^ sw));
        o[nj] = __builtin_amdgcn_mfma_f32_16x16x32_bf16(pf, vf, o[nj], 0, 0, 0);
      }
    }
    __builtin_amdgcn_s_setprio(0);
    __syncthreads();
  }

  float inv[4];
#pragma unroll
  for (int j = 0; j < 4; ++j) inv[j] = 1.0f / lsum[j];
  const int b = bh >> 4, h = bh & 15;
#pragma unroll
  for (int nj = 0; nj < 8; ++nj)
#pragma unroll
    for (int j = 0; j < 4; ++j) {
      const int q = q0 + roff + j;
      const int d = nj * 16 + lr;
      O[(long)(b * T + q) * 2048 + h * 128 + d] = f2b(o[nj][j] * inv[j]);
    }
}

// ---------------- launch ----------------
extern "C" void kernel_launch(void* const* d_in, const int* in_sizes, int n_in,
                              void* d_out, int out_size, void* d_ws, size_t ws_size,
                              hipStream_t stream)
{
  const int B = 2, T = 2048, C = 2048;
  const int M = B * T;        // 4096
  const int N1 = 3 * C;       // 6144
  const float* x    = (const float*)d_in[0];
  const float* Wqkv = (const float*)d_in[1];
  const float* bqkv = (const float*)d_in[2];
  const float* Wout = (const float*)d_in[3];
  const float* bout = (const float*)d_in[4];
  float* out = (float*)d_out;

  char* p = (char*)d_ws;
  unsigned short* xb    = (unsigned short*)p; p += (size_t)M * C * 2;
  unsigned short* wqkvb = (unsigned short*)p; p += (size_t)N1 * C * 2;
  unsigned short* woutb = (unsigned short*)p; p += (size_t)C * C * 2;
  unsigned short* qkv   = (unsigned short*)p; p += (size_t)M * N1 * 2;
  unsigned short* Qr    = (unsigned short*)p; p += (size_t)M * C * 2;
  unsigned short* Kr    = (unsigned short*)p; p += (size_t)M * C * 2;
  unsigned short* Vt    = (unsigned short*)p; p += (size_t)M * C * 2;
  unsigned short* Ob    = xb;  // xb dead after QKV GEMM

  cast_kernel<<<M * C / 1024, 256, 0, stream>>>(x, xb, M * C);
  cast_kernel<<<N1 * C / 1024, 256, 0, stream>>>(Wqkv, wqkvb, N1 * C);
  cast_kernel<<<C * C / 1024, 256, 0, stream>>>(Wout, woutb, C * C);

  gemm128<0><<<dim3((M / 128) * (N1 / 256)), 512, 0, stream>>>(xb, wqkvb, bqkv, qkv, M, N1, C);

  prep_kernel<<<dim3(T / 64, 32), 256, 0, stream>>>(qkv, Qr, Kr, Vt);

  attn_fwd<<<dim3(32, T / 64), 256, 0, stream>>>(Qr, Kr, Vt, Ob, T);

  gemm128<1><<<dim3((M / 128) * (C / 256)), 512, 0, stream>>>(Ob, woutb, bout, out, M, C, C);
}

// Round 10
// 290.769 us; speedup vs baseline: 1.2746x; 1.0576x over previous
//
#include <hip/hip_runtime.h>
#include <hip/hip_bf16.h>

typedef __attribute__((ext_vector_type(8))) short bf16x8;
typedef __attribute__((ext_vector_type(4))) float f32x4;

#define GLOAD_LDS16(gptr, lptr) \
  __builtin_amdgcn_global_load_lds((const __attribute__((address_space(1))) void*)(gptr), \
                                   (__attribute__((address_space(3))) void*)(lptr), 16, 0, 0)

__device__ __forceinline__ unsigned short f2b(float f) {
  union { float f; unsigned u; } x; x.f = f;
  unsigned r = x.u + 0x7fffu + ((x.u >> 16) & 1u);
  return (unsigned short)(r >> 16);
}
__device__ __forceinline__ float b2f(unsigned short u) {
  union { unsigned u; float f; } x; x.u = ((unsigned)u) << 16;
  return x.f;
}
__device__ __forceinline__ unsigned cvt_pk_bf16(float lo, float hi) {
  unsigned d;
  asm("v_cvt_pk_bf16_f32 %0, %1, %2" : "=v"(d) : "v"(lo), "v"(hi));
  return d;
}

// ---------------- fp32 -> bf16 cast ----------------
__global__ void cast_kernel(const float* __restrict__ in, unsigned short* __restrict__ out, int n) {
  const int i = (blockIdx.x * 256 + threadIdx.x) * 4;
  if (i < n) {
    const float4 v = *(const float4*)(in + i);
    ushort4 r;
    r.x = f2b(v.x); r.y = f2b(v.y); r.z = f2b(v.z); r.w = f2b(v.w);
    *(ushort4*)(out + i) = r;
  }
}

// ---------------- GEMM 128x256, BK=32, 3-slot LDS, 2 blocks/CU (frozen at R8) ----------------
template<int OUTF32>
__global__ __launch_bounds__(512, 4)
void gemm128(const unsigned short* __restrict__ A,
             const unsigned short* __restrict__ Bm,
             const float* __restrict__ bias,
             void* __restrict__ Cp,
             int M, int N, int K)
{
  __shared__ __align__(16) char Lds[73728];   // 3 slots x (A 8KB | B 16KB)
  const int t  = threadIdx.x;
  const int l  = t & 63;
  const int w  = t >> 6;
  const int lr = l & 15;
  const int lkb = (l >> 4) << 4;
  const int wr = w >> 2;
  const int wc = w & 3;

  const int nwg = gridDim.x;
  const int wg  = (blockIdx.x & 7) * (nwg >> 3) + (blockIdx.x >> 3);
  const int NBN = N >> 8;
  const int bm = wg / NBN, bn = wg % NBN;

  const long K2 = (long)K * 2;
  const char* Ab = (const char*)A  + (long)(bm * 128) * K2;
  const char* Bb = (const char*)Bm + (long)(bn * 256) * K2;

  auto swz = [](int a) -> int { return a ^ (((a >> 7) & 3) << 4); };

  const int t16 = t << 4;
  const int da  = swz(t16);
  const long sa = (long)(da >> 6) * K2 + (da & 63);
  const int db0 = swz(t16), db1 = swz(8192 + t16);
  const long sb0 = (long)(db0 >> 6) * K2 + (db0 & 63);
  const long sb1 = (long)(db1 >> 6) * K2 + (db1 & 63);

  auto stage = [&](int g) {
    char* S = Lds + (g % 3) * 24576;
    const char* As = Ab + (long)g * 64;
    const char* Bs = Bb + (long)g * 64;
    GLOAD_LDS16(As + sa,  S + t16);
    GLOAD_LDS16(Bs + sb0, S + 8192 + t16);
    GLOAD_LDS16(Bs + sb1, S + 16384 + t16);
  };

  int aoff[4], boff[4];
#pragma unroll
  for (int mi = 0; mi < 4; ++mi) {
    const int a = ((wr * 64 + mi * 16 + lr) << 6) | lkb;
    aoff[mi] = swz(a);
  }
#pragma unroll
  for (int ni = 0; ni < 4; ++ni) {
    const int a = ((wc * 64 + ni * 16 + lr) << 6) | lkb;
    boff[ni] = 8192 + swz(a);
  }

  f32x4 acc[4][4] = {};
  const int NT = K >> 5;
  bf16x8 af[4], bfr[4];

  stage(0); stage(1);
  asm volatile("s_waitcnt vmcnt(3)" ::: "memory");
  __builtin_amdgcn_s_barrier();
  __builtin_amdgcn_sched_barrier(0);
#pragma unroll
  for (int mi = 0; mi < 4; ++mi) af[mi]  = *(const bf16x8*)(Lds + aoff[mi]);
#pragma unroll
  for (int ni = 0; ni < 4; ++ni) bfr[ni] = *(const bf16x8*)(Lds + boff[ni]);

  for (int tt = 0; tt < NT; ++tt) {
    if (tt + 2 < NT) stage(tt + 2);
    __builtin_amdgcn_s_setprio(1);
#pragma unroll
    for (int mi = 0; mi < 4; ++mi)
#pragma unroll
      for (int ni = 0; ni < 4; ++ni)
        acc[mi][ni] = __builtin_amdgcn_mfma_f32_16x16x32_bf16(af[mi], bfr[ni], acc[mi][ni], 0, 0, 0);
    __builtin_amdgcn_s_setprio(0);
    if (tt + 1 < NT) {
      if (tt + 2 < NT) asm volatile("s_waitcnt vmcnt(3)" ::: "memory");
      else             asm volatile("s_waitcnt vmcnt(0)" ::: "memory");
      __builtin_amdgcn_s_barrier();
      __builtin_amdgcn_sched_barrier(0);
      const char* S = Lds + ((tt + 1) % 3) * 24576;
#pragma unroll
      for (int mi = 0; mi < 4; ++mi) af[mi]  = *(const bf16x8*)(S + aoff[mi]);
#pragma unroll
      for (int ni = 0; ni < 4; ++ni) bfr[ni] = *(const bf16x8*)(S + boff[ni]);
    }
  }

  const int roff = (l >> 4) << 2;
  const int row0 = bm * 128 + wr * 64 + roff;
  const int col0 = bn * 256 + wc * 64 + lr;
  float bv[4];
#pragma unroll
  for (int ni = 0; ni < 4; ++ni) bv[ni] = bias ? bias[col0 + ni * 16] : 0.0f;
#pragma unroll
  for (int mi = 0; mi < 4; ++mi) {
#pragma unroll
    for (int r = 0; r < 4; ++r) {
      const long rb = (long)(row0 + mi * 16 + r) * N;
#pragma unroll
      for (int ni = 0; ni < 4; ++ni) {
        const float v = acc[mi][ni][r] + bv[ni];
        if (OUTF32) ((float*)Cp)[rb + col0 + ni * 16] = v;
        else ((unsigned short*)Cp)[rb + col0 + ni * 16] = f2b(v);
      }
    }
  }
}

// ---------------- fused RoPE + V-transpose ----------------
__global__ void prep_kernel(const unsigned short* __restrict__ qkv,
                            unsigned short* __restrict__ Qr,
                            unsigned short* __restrict__ Kr,
                            unsigned short* __restrict__ Vt)
{
  const int T = 2048;
  __shared__ unsigned short ld[128][65];
  const int bh = blockIdx.y, tb = blockIdx.x;
  const int b = bh >> 4, h = bh & 15;
  const int t = threadIdx.x;

#pragma unroll
  for (int i = 0; i < 16; ++i) {
    const int idx = i * 256 + t;
    const int d  = idx & 63;
    const int tt = tb * 64 + (idx >> 6);
    const long base = ((long)(b * T + tt) * 3) * 2048 + h * 128;
    const float inv = exp2f(-(float)d * 0.2076205059304602f);
    const float fr = (float)tt * inv;
    float sn, cs;
    sincosf(fr, &sn, &cs);
    const float q1 = b2f(qkv[base + 2 * d]);
    const float q2 = b2f(qkv[base + 2 * d + 1]);
    const float k1 = b2f(qkv[base + 2048 + 2 * d]);
    const float k2 = b2f(qkv[base + 2048 + 2 * d + 1]);
    const long ob = ((long)bh * T + tt) * 128;
    Qr[ob + d]      = f2b(q1 * cs - q2 * sn);
    Qr[ob + 64 + d] = f2b(q1 * sn + q2 * cs);
    Kr[ob + d]      = f2b(k1 * cs - k2 * sn);
    Kr[ob + 64 + d] = f2b(k1 * sn + k2 * cs);
  }

#pragma unroll
  for (int i = 0; i < 32; ++i) {
    const int idx = i * 256 + t;
    const int d = idx & 127, tr = idx >> 7;
    ld[d][tr] = qkv[((long)(b * T + tb * 64 + tr) * 3 + 2) * 2048 + h * 128 + d];
  }
  __syncthreads();
#pragma unroll
  for (int i = 0; i < 32; ++i) {
    const int idx = i * 256 + t;
    const int tc = idx & 63, dr = idx >> 6;
    Vt[((long)bh * 128 + dr) * T + tb * 64 + tc] = ld[dr][tc];
  }
}

// ---------------- causal flash attention: swapped QK^T, in-register softmax/P ----------------
// S^T = mfma(K,Q): lane owns full P-row for q = lane&15 (16 vals) -> in-lane max/sum,
// scalar m/lsum, P->A-frag via cvt_pk + shfl (no Ps LDS, no scalar stores).
__global__ __launch_bounds__(256)
void attn_fwd(const unsigned short* __restrict__ Q,
              const unsigned short* __restrict__ Kg,
              const unsigned short* __restrict__ Vt,
              unsigned short* __restrict__ O, int T)
{
  __shared__ __align__(16) unsigned short Ks[2][64 * 128];
  __shared__ __align__(16) unsigned short Vs[2][128 * 64];
  const int t = threadIdx.x;
  const int w = t >> 6, l = t & 63;
  const int lr = l & 15;
  const int g  = l >> 4;
  const int g16 = g << 4;
  const int sw = (lr & 7) << 4;
  const int bh = blockIdx.x;
  const int qt = (gridDim.y - 1) - blockIdx.y;
  const int q0 = qt * 64 + w * 16;
  const long hbase = (long)bh * T * 128;
  const long hbase2 = hbase * 2;
  const long T2 = (long)T * 2;
  const int roff = g << 2;
  const float C1 = 0.08838834764831845f * 1.4426950408889634f;  // 1/sqrt(128)*log2(e)

  bf16x8 qf[4];
  const unsigned short* Qrow = Q + hbase + (long)(q0 + lr) * 128;
#pragma unroll
  for (int ds = 0; ds < 4; ++ds) qf[ds] = *(const bf16x8*)&Qrow[ds * 32 + (g16 >> 1)];

  f32x4 o[8] = {};
  float m = -INFINITY, lsum = 0.f;

  auto stage = [&](int kt, int buf) {
#pragma unroll
    for (int c = 0; c < 4; ++c) {
      const int o2 = t * 16 + c * 4096;
      const int krow = o2 >> 8, kcb = o2 & 255;
      GLOAD_LDS16((const char*)Kg + hbase2 + (long)kt * 16384 + krow * 256 + (kcb ^ ((krow & 7) << 4)),
                  (char*)Ks[buf] + o2);
      const int vrow = o2 >> 7, vcb = o2 & 127;
      GLOAD_LDS16((const char*)Vt + (long)(bh * 128 + vrow) * T2 + (long)kt * 128 + (vcb ^ ((vrow & 7) << 4)),
                  (char*)Vs[buf] + o2);
    }
  };

  const int ntile = qt + 1;
  stage(0, 0);
  __syncthreads();

  for (int kt = 0; kt < ntile; ++kt) {
    const int cur = kt & 1;
    if (kt + 1 < ntile) stage(kt + 1, cur ^ 1);

    const char* KsB = (const char*)Ks[cur];
    const char* VsB = (const char*)Vs[cur];

    // S^T tiles: s[tj] holds S[kv = kt*64+tj*16+4g+r][q = q0+lr]
    f32x4 s[4] = {};
    __builtin_amdgcn_s_setprio(1);
#pragma unroll
    for (int tj = 0; tj < 4; ++tj)
#pragma unroll
      for (int ds = 0; ds < 4; ++ds) {
        bf16x8 kf = *(const bf16x8*)(KsB + (tj * 16 + lr) * 256 + ((ds * 64 + g16) ^ sw));
        s[tj] = __builtin_amdgcn_mfma_f32_16x16x32_bf16(kf, qf[ds], s[tj], 0, 0, 0);
      }
    __builtin_amdgcn_s_setprio(0);

    if (kt == qt) {
#pragma unroll
      for (int tj = 0; tj < 4; ++tj)
#pragma unroll
        for (int r = 0; r < 4; ++r)
          if (kt * 64 + tj * 16 + 4 * g + r > q0 + lr) s[tj][r] = -INFINITY;
    }

    // in-lane row max over 16 vals + cross-group reduce
    float pmax = -INFINITY;
#pragma unroll
    for (int tj = 0; tj < 4; ++tj)
#pragma unroll
      for (int r = 0; r < 4; ++r) pmax = fmaxf(pmax, s[tj][r]);
    pmax = fmaxf(pmax, __shfl_xor(pmax, 16, 64));
    pmax = fmaxf(pmax, __shfl_xor(pmax, 32, 64));
    const float mn = fmaxf(m, pmax * C1);
    const float corr = exp2f(m - mn);
    m = mn;

    float p[4][4];
    float rs = 0.f;
#pragma unroll
    for (int tj = 0; tj < 4; ++tj)
#pragma unroll
      for (int r = 0; r < 4; ++r) {
        const float pv = exp2f(fmaf(s[tj][r], C1, -mn));
        p[tj][r] = pv;
        rs += pv;
      }
    rs += __shfl_xor(rs, 16, 64);
    rs += __shfl_xor(rs, 32, 64);
    lsum = lsum * corr + rs;

    // pack P pairs: D8[tj][h] = bf16{p[tj][2h] (lo), p[tj][2h+1] (hi)}
    unsigned D8[4][2];
#pragma unroll
    for (int tj = 0; tj < 4; ++tj) {
      D8[tj][0] = cvt_pk_bf16(p[tj][0], p[tj][1]);
      D8[tj][1] = cvt_pk_bf16(p[tj][2], p[tj][3]);
    }

    // rescale O (O rows q = 4g+r): fetch corr per reg from lanes 0-15
    float corrj[4];
#pragma unroll
    for (int j = 0; j < 4; ++j) corrj[j] = __shfl(corr, roff + j, 64);
#pragma unroll
    for (int nj = 0; nj < 8; ++nj)
#pragma unroll
      for (int j = 0; j < 4; ++j) o[nj][j] *= corrj[j];

    // build P A-frags in-register and do PV
    __builtin_amdgcn_s_setprio(1);
#pragma unroll
    for (int ks = 0; ks < 2; ++ks) {
      union { unsigned u[4]; bf16x8 v; } pfu;
#pragma unroll
      for (int k2 = 0; k2 < 4; ++k2) {
        const int src = lr | ((2 * (g & 1) + (k2 >> 1)) << 4);
        const unsigned dwA = __shfl(D8[2 * ks][k2 & 1], src, 64);
        const unsigned dwB = __shfl(D8[2 * ks + 1][k2 & 1], src, 64);
        pfu.u[k2] = (g & 2) ? dwB : dwA;
      }
#pragma unroll
      for (int nj = 0; nj < 8; ++nj) {
        bf16x8 vf = *(const bf16x8*)(VsB + (nj * 16 + lr) * 128 + ((ks * 64 + g16) ^ sw));
        o[nj] = __builtin_amdgcn_mfma_f32_16x16x32_bf16(pfu.v, vf, o[nj], 0, 0, 0);
      }
    }
    __builtin_amdgcn_s_setprio(0);
    __syncthreads();
  }

  const float inv = 1.0f / lsum;
  float invj[4];
#pragma unroll
  for (int j = 0; j < 4; ++j) invj[j] = __shfl(inv, roff + j, 64);
  const int b = bh >> 4, h = bh & 15;
#pragma unroll
  for (int nj = 0; nj < 8; ++nj)
#pragma unroll
    for (int j = 0; j < 4; ++j) {
      const int q = q0 + roff + j;
      const int d = nj * 16 + lr;
      O[(long)(b * T + q) * 2048 + h * 128 + d] = f2b(o[nj][j] * invj[j]);
    }
}

// ---------------- launch ----------------
extern "C" void kernel_launch(void* const* d_in, const int* in_sizes, int n_in,
                              void* d_out, int out_size, void* d_ws, size_t ws_size,
                              hipStream_t stream)
{
  const int B = 2, T = 2048, C = 2048;
  const int M = B * T;        // 4096
  const int N1 = 3 * C;       // 6144
  const float* x    = (const float*)d_in[0];
  const float* Wqkv = (const float*)d_in[1];
  const float* bqkv = (const float*)d_in[2];
  const float* Wout = (const float*)d_in[3];
  const float* bout = (const float*)d_in[4];
  float* out = (float*)d_out;

  char* p = (char*)d_ws;
  unsigned short* xb    = (unsigned short*)p; p += (size_t)M * C * 2;
  unsigned short* wqkvb = (unsigned short*)p; p += (size_t)N1 * C * 2;
  unsigned short* woutb = (unsigned short*)p; p += (size_t)C * C * 2;
  unsigned short* qkv   = (unsigned short*)p; p += (size_t)M * N1 * 2;
  unsigned short* Qr    = (unsigned short*)p; p += (size_t)M * C * 2;
  unsigned short* Kr    = (unsigned short*)p; p += (size_t)M * C * 2;
  unsigned short* Vt    = (unsigned short*)p; p += (size_t)M * C * 2;
  unsigned short* Ob    = xb;  // xb dead after QKV GEMM

  cast_kernel<<<M * C / 1024, 256, 0, stream>>>(x, xb, M * C);
  cast_kernel<<<N1 * C / 1024, 256, 0, stream>>>(Wqkv, wqkvb, N1 * C);
  cast_kernel<<<C * C / 1024, 256, 0, stream>>>(Wout, woutb, C * C);

  gemm128<0><<<dim3((M / 128) * (N1 / 256)), 512, 0, stream>>>(xb, wqkvb, bqkv, qkv, M, N1, C);

  prep_kernel<<<dim3(T / 64, 32), 256, 0, stream>>>(qkv, Qr, Kr, Vt);

  attn_fwd<<<dim3(32, T / 64), 256, 0, stream>>>(Qr, Kr, Vt, Ob, T);

  gemm128<1><<<dim3((M / 128) * (C / 256)), 512, 0, stream>>>(Ob, woutb, bout, out, M, C, C);
}

// Round 11
// 286.514 us; speedup vs baseline: 1.2935x; 1.0149x over previous
//
#include <hip/hip_runtime.h>
#include <hip/hip_bf16.h>

typedef __attribute__((ext_vector_type(8))) short bf16x8;
typedef __attribute__((ext_vector_type(4))) float f32x4;

#define GLOAD_LDS16(gptr, lptr) \
  __builtin_amdgcn_global_load_lds((const __attribute__((address_space(1))) void*)(gptr), \
                                   (__attribute__((address_space(3))) void*)(lptr), 16, 0, 0)

__device__ __forceinline__ unsigned short f2b(float f) {
  union { float f; unsigned u; } x; x.f = f;
  unsigned r = x.u + 0x7fffu + ((x.u >> 16) & 1u);
  return (unsigned short)(r >> 16);
}
__device__ __forceinline__ float b2f(unsigned short u) {
  union { unsigned u; float f; } x; x.u = ((unsigned)u) << 16;
  return x.f;
}
__device__ __forceinline__ unsigned cvt_pk_bf16(float lo, float hi) {
  unsigned d;
  asm("v_cvt_pk_bf16_f32 %0, %1, %2" : "=v"(d) : "v"(lo), "v"(hi));
  return d;
}

// ---------------- fused fp32 -> bf16 cast (x | W_qkv | W_out -> contiguous ws) ----------------
__global__ void cast3_kernel(const float* __restrict__ x,
                             const float* __restrict__ wq,
                             const float* __restrict__ wo,
                             unsigned short* __restrict__ out)
{
  const long n1 = 8388608L;    // M*C
  const long n2 = 20971520L;   // + N1*C
  const long i = ((long)blockIdx.x * 256 + threadIdx.x) * 4;
  const float* src; long off;
  if (i < n1)      { src = x;  off = i; }
  else if (i < n2) { src = wq; off = i - n1; }
  else             { src = wo; off = i - n2; }
  const float4 v = *(const float4*)(src + off);
  ushort4 r;
  r.x = f2b(v.x); r.y = f2b(v.y); r.z = f2b(v.z); r.w = f2b(v.w);
  *(ushort4*)(out + i) = r;
}

// ---------------- GEMM 128x256, BK=32, 3-slot LDS, 2 blocks/CU (frozen at R8) ----------------
template<int OUTF32>
__global__ __launch_bounds__(512, 4)
void gemm128(const unsigned short* __restrict__ A,
             const unsigned short* __restrict__ Bm,
             const float* __restrict__ bias,
             void* __restrict__ Cp,
             int M, int N, int K)
{
  __shared__ __align__(16) char Lds[73728];   // 3 slots x (A 8KB | B 16KB)
  const int t  = threadIdx.x;
  const int l  = t & 63;
  const int w  = t >> 6;
  const int lr = l & 15;
  const int lkb = (l >> 4) << 4;
  const int wr = w >> 2;
  const int wc = w & 3;

  const int nwg = gridDim.x;
  const int wg  = (blockIdx.x & 7) * (nwg >> 3) + (blockIdx.x >> 3);
  const int NBN = N >> 8;
  const int bm = wg / NBN, bn = wg % NBN;

  const long K2 = (long)K * 2;
  const char* Ab = (const char*)A  + (long)(bm * 128) * K2;
  const char* Bb = (const char*)Bm + (long)(bn * 256) * K2;

  auto swz = [](int a) -> int { return a ^ (((a >> 7) & 3) << 4); };

  const int t16 = t << 4;
  const int da  = swz(t16);
  const long sa = (long)(da >> 6) * K2 + (da & 63);
  const int db0 = swz(t16), db1 = swz(8192 + t16);
  const long sb0 = (long)(db0 >> 6) * K2 + (db0 & 63);
  const long sb1 = (long)(db1 >> 6) * K2 + (db1 & 63);

  auto stage = [&](int g) {
    char* S = Lds + (g % 3) * 24576;
    const char* As = Ab + (long)g * 64;
    const char* Bs = Bb + (long)g * 64;
    GLOAD_LDS16(As + sa,  S + t16);
    GLOAD_LDS16(Bs + sb0, S + 8192 + t16);
    GLOAD_LDS16(Bs + sb1, S + 16384 + t16);
  };

  int aoff[4], boff[4];
#pragma unroll
  for (int mi = 0; mi < 4; ++mi) {
    const int a = ((wr * 64 + mi * 16 + lr) << 6) | lkb;
    aoff[mi] = swz(a);
  }
#pragma unroll
  for (int ni = 0; ni < 4; ++ni) {
    const int a = ((wc * 64 + ni * 16 + lr) << 6) | lkb;
    boff[ni] = 8192 + swz(a);
  }

  f32x4 acc[4][4] = {};
  const int NT = K >> 5;
  bf16x8 af[4], bfr[4];

  stage(0); stage(1);
  asm volatile("s_waitcnt vmcnt(3)" ::: "memory");
  __builtin_amdgcn_s_barrier();
  __builtin_amdgcn_sched_barrier(0);
#pragma unroll
  for (int mi = 0; mi < 4; ++mi) af[mi]  = *(const bf16x8*)(Lds + aoff[mi]);
#pragma unroll
  for (int ni = 0; ni < 4; ++ni) bfr[ni] = *(const bf16x8*)(Lds + boff[ni]);

  for (int tt = 0; tt < NT; ++tt) {
    if (tt + 2 < NT) stage(tt + 2);
    __builtin_amdgcn_s_setprio(1);
#pragma unroll
    for (int mi = 0; mi < 4; ++mi)
#pragma unroll
      for (int ni = 0; ni < 4; ++ni)
        acc[mi][ni] = __builtin_amdgcn_mfma_f32_16x16x32_bf16(af[mi], bfr[ni], acc[mi][ni], 0, 0, 0);
    __builtin_amdgcn_s_setprio(0);
    if (tt + 1 < NT) {
      if (tt + 2 < NT) asm volatile("s_waitcnt vmcnt(3)" ::: "memory");
      else             asm volatile("s_waitcnt vmcnt(0)" ::: "memory");
      __builtin_amdgcn_s_barrier();
      __builtin_amdgcn_sched_barrier(0);
      const char* S = Lds + ((tt + 1) % 3) * 24576;
#pragma unroll
      for (int mi = 0; mi < 4; ++mi) af[mi]  = *(const bf16x8*)(S + aoff[mi]);
#pragma unroll
      for (int ni = 0; ni < 4; ++ni) bfr[ni] = *(const bf16x8*)(S + boff[ni]);
    }
  }

  const int roff = (l >> 4) << 2;
  const int row0 = bm * 128 + wr * 64 + roff;
  const int col0 = bn * 256 + wc * 64 + lr;
  float bv[4];
#pragma unroll
  for (int ni = 0; ni < 4; ++ni) bv[ni] = bias ? bias[col0 + ni * 16] : 0.0f;
#pragma unroll
  for (int mi = 0; mi < 4; ++mi) {
#pragma unroll
    for (int r = 0; r < 4; ++r) {
      const long rb = (long)(row0 + mi * 16 + r) * N;
#pragma unroll
      for (int ni = 0; ni < 4; ++ni) {
        const float v = acc[mi][ni][r] + bv[ni];
        if (OUTF32) ((float*)Cp)[rb + col0 + ni * 16] = v;
        else ((unsigned short*)Cp)[rb + col0 + ni * 16] = f2b(v);
      }
    }
  }
}

// ---------------- fused RoPE + V-transpose ----------------
__global__ void prep_kernel(const unsigned short* __restrict__ qkv,
                            unsigned short* __restrict__ Qr,
                            unsigned short* __restrict__ Kr,
                            unsigned short* __restrict__ Vt)
{
  const int T = 2048;
  __shared__ unsigned short ld[128][65];
  const int bh = blockIdx.y, tb = blockIdx.x;
  const int b = bh >> 4, h = bh & 15;
  const int t = threadIdx.x;

#pragma unroll
  for (int i = 0; i < 16; ++i) {
    const int idx = i * 256 + t;
    const int d  = idx & 63;
    const int tt = tb * 64 + (idx >> 6);
    const long base = ((long)(b * T + tt) * 3) * 2048 + h * 128;
    const float inv = exp2f(-(float)d * 0.2076205059304602f);
    const float fr = (float)tt * inv;
    float sn, cs;
    sincosf(fr, &sn, &cs);
    const float q1 = b2f(qkv[base + 2 * d]);
    const float q2 = b2f(qkv[base + 2 * d + 1]);
    const float k1 = b2f(qkv[base + 2048 + 2 * d]);
    const float k2 = b2f(qkv[base + 2048 + 2 * d + 1]);
    const long ob = ((long)bh * T + tt) * 128;
    Qr[ob + d]      = f2b(q1 * cs - q2 * sn);
    Qr[ob + 64 + d] = f2b(q1 * sn + q2 * cs);
    Kr[ob + d]      = f2b(k1 * cs - k2 * sn);
    Kr[ob + 64 + d] = f2b(k1 * sn + k2 * cs);
  }

#pragma unroll
  for (int i = 0; i < 32; ++i) {
    const int idx = i * 256 + t;
    const int d = idx & 127, tr = idx >> 7;
    ld[d][tr] = qkv[((long)(b * T + tb * 64 + tr) * 3 + 2) * 2048 + h * 128 + d];
  }
  __syncthreads();
#pragma unroll
  for (int i = 0; i < 32; ++i) {
    const int idx = i * 256 + t;
    const int tc = idx & 63, dr = idx >> 6;
    Vt[((long)bh * 128 + dr) * T + tb * 64 + tc] = ld[dr][tc];
  }
}

// ---------------- causal flash attention: swapped QK^T, in-reg softmax, single-V LDS ----------------
// K double-buffered (32KB) + V single buffer (16KB) = 48KB -> 3 blocks/CU.
// Sync per tile: vmcnt(4)+s_barrier before PV (own V landed + all waves), __syncthreads
// at end (frees Vs), stage V(t+1) after. Defer-max (T13, THR=8 in exp2 domain).
__global__ __launch_bounds__(256)
void attn_fwd(const unsigned short* __restrict__ Q,
              const unsigned short* __restrict__ Kg,
              const unsigned short* __restrict__ Vt,
              unsigned short* __restrict__ O, int T)
{
  __shared__ __align__(16) unsigned short Ks[2][64 * 128];
  __shared__ __align__(16) unsigned short Vs[128 * 64];
  const int t = threadIdx.x;
  const int w = t >> 6, l = t & 63;
  const int lr = l & 15;
  const int g  = l >> 4;
  const int g16 = g << 4;
  const int sw = (lr & 7) << 4;
  const int bh = blockIdx.x;
  const int qt = (gridDim.y - 1) - blockIdx.y;
  const int q0 = qt * 64 + w * 16;
  const long hbase = (long)bh * T * 128;
  const long hbase2 = hbase * 2;
  const long T2 = (long)T * 2;
  const int roff = g << 2;
  const float C1 = 0.08838834764831845f * 1.4426950408889634f;  // 1/sqrt(128)*log2(e)

  bf16x8 qf[4];
  const unsigned short* Qrow = Q + hbase + (long)(q0 + lr) * 128;
#pragma unroll
  for (int ds = 0; ds < 4; ++ds) qf[ds] = *(const bf16x8*)&Qrow[ds * 32 + (g16 >> 1)];

  f32x4 o[8] = {};
  float m = -INFINITY, lsum = 0.f;

  auto stageK = [&](int kt, int buf) {
#pragma unroll
    for (int c = 0; c < 4; ++c) {
      const int o2 = t * 16 + c * 4096;
      const int krow = o2 >> 8, kcb = o2 & 255;
      GLOAD_LDS16((const char*)Kg + hbase2 + (long)kt * 16384 + krow * 256 + (kcb ^ ((krow & 7) << 4)),
                  (char*)Ks[buf] + o2);
    }
  };
  auto stageV = [&](int kt) {
#pragma unroll
    for (int c = 0; c < 4; ++c) {
      const int o2 = t * 16 + c * 4096;
      const int vrow = o2 >> 7, vcb = o2 & 127;
      GLOAD_LDS16((const char*)Vt + (long)(bh * 128 + vrow) * T2 + (long)kt * 128 + (vcb ^ ((vrow & 7) << 4)),
                  (char*)Vs + o2);
    }
  };

  const int ntile = qt + 1;
  stageK(0, 0);
  stageV(0);
  __syncthreads();

  for (int kt = 0; kt < ntile; ++kt) {
    const int cur = kt & 1;
    if (kt + 1 < ntile) stageK(kt + 1, cur ^ 1);

    const char* KsB = (const char*)Ks[cur];

    // S^T: s[tj] = S[kv = kt*64+tj*16+4g+r][q = q0+lr]
    f32x4 s[4] = {};
    __builtin_amdgcn_s_setprio(1);
#pragma unroll
    for (int tj = 0; tj < 4; ++tj)
#pragma unroll
      for (int ds = 0; ds < 4; ++ds) {
        bf16x8 kf = *(const bf16x8*)(KsB + (tj * 16 + lr) * 256 + ((ds * 64 + g16) ^ sw));
        s[tj] = __builtin_amdgcn_mfma_f32_16x16x32_bf16(kf, qf[ds], s[tj], 0, 0, 0);
      }
    __builtin_amdgcn_s_setprio(0);

    if (kt == qt) {
#pragma unroll
      for (int tj = 0; tj < 4; ++tj)
#pragma unroll
        for (int r = 0; r < 4; ++r)
          if (kt * 64 + tj * 16 + 4 * g + r > q0 + lr) s[tj][r] = -INFINITY;
    }

    float pmax = -INFINITY;
#pragma unroll
    for (int tj = 0; tj < 4; ++tj)
#pragma unroll
      for (int r = 0; r < 4; ++r) pmax = fmaxf(pmax, s[tj][r]);
    pmax = fmaxf(pmax, __shfl_xor(pmax, 16, 64));
    pmax = fmaxf(pmax, __shfl_xor(pmax, 32, 64));
    const float pm = pmax * C1;

    // defer-max: only rescale when some row grew by > 8 (exp2 domain)
    const bool need = !__all(pm - m <= 8.0f);
    float corr = 1.0f;
    if (need) {
      const float mn = fmaxf(m, pm);
      corr = exp2f(m - mn);
      m = mn;
    }

    float p[4][4];
    float rs = 0.f;
#pragma unroll
    for (int tj = 0; tj < 4; ++tj)
#pragma unroll
      for (int r = 0; r < 4; ++r) {
        const float pv = exp2f(fmaf(s[tj][r], C1, -m));
        p[tj][r] = pv;
        rs += pv;
      }
    rs += __shfl_xor(rs, 16, 64);
    rs += __shfl_xor(rs, 32, 64);
    lsum = lsum * corr + rs;

    unsigned D8[4][2];
#pragma unroll
    for (int tj = 0; tj < 4; ++tj) {
      D8[tj][0] = cvt_pk_bf16(p[tj][0], p[tj][1]);
      D8[tj][1] = cvt_pk_bf16(p[tj][2], p[tj][3]);
    }

    if (need) {
      float corrj[4];
#pragma unroll
      for (int j = 0; j < 4; ++j) corrj[j] = __shfl(corr, roff + j, 64);
#pragma unroll
      for (int nj = 0; nj < 8; ++nj)
#pragma unroll
        for (int j = 0; j < 4; ++j) o[nj][j] *= corrj[j];
    }

    // own V loads landed (4 K-loads may remain in flight); all waves at barrier
    if (kt + 1 < ntile) asm volatile("s_waitcnt vmcnt(4)" ::: "memory");
    else                asm volatile("s_waitcnt vmcnt(0)" ::: "memory");
    __builtin_amdgcn_s_barrier();
    __builtin_amdgcn_sched_barrier(0);

    __builtin_amdgcn_s_setprio(1);
#pragma unroll
    for (int ks = 0; ks < 2; ++ks) {
      union { unsigned u[4]; bf16x8 v; } pfu;
#pragma unroll
      for (int k2 = 0; k2 < 4; ++k2) {
        const int src = lr | ((2 * (g & 1) + (k2 >> 1)) << 4);
        const unsigned dwA = __shfl(D8[2 * ks][k2 & 1], src, 64);
        const unsigned dwB = __shfl(D8[2 * ks + 1][k2 & 1], src, 64);
        pfu.u[k2] = (g & 2) ? dwB : dwA;
      }
#pragma unroll
      for (int nj = 0; nj < 8; ++nj) {
        bf16x8 vf = *(const bf16x8*)((const char*)Vs + (nj * 16 + lr) * 128 + ((ks * 64 + g16) ^ sw));
        o[nj] = __builtin_amdgcn_mfma_f32_16x16x32_bf16(pfu.v, vf, o[nj], 0, 0, 0);
      }
    }
    __builtin_amdgcn_s_setprio(0);

    __syncthreads();                       // all waves done with Vs + Ks[cur]
    if (kt + 1 < ntile) stageV(kt + 1);    // safe overwrite of single V buffer
  }

  const float inv = 1.0f / lsum;
  float invj[4];
#pragma unroll
  for (int j = 0; j < 4; ++j) invj[j] = __shfl(inv, roff + j, 64);
  const int b = bh >> 4, h = bh & 15;
#pragma unroll
  for (int nj = 0; nj < 8; ++nj)
#pragma unroll
    for (int j = 0; j < 4; ++j) {
      const int q = q0 + roff + j;
      const int d = nj * 16 + lr;
      O[(long)(b * T + q) * 2048 + h * 128 + d] = f2b(o[nj][j] * invj[j]);
    }
}

// ---------------- launch ----------------
extern "C" void kernel_launch(void* const* d_in, const int* in_sizes, int n_in,
                              void* d_out, int out_size, void* d_ws, size_t ws_size,
                              hipStream_t stream)
{
  const int B = 2, T = 2048, C = 2048;
  const int M = B * T;        // 4096
  const int N1 = 3 * C;       // 6144
  const float* x    = (const float*)d_in[0];
  const float* Wqkv = (const float*)d_in[1];
  const float* bqkv = (const float*)d_in[2];
  const float* Wout = (const float*)d_in[3];
  const float* bout = (const float*)d_in[4];
  float* out = (float*)d_out;

  char* p = (char*)d_ws;
  unsigned short* xb    = (unsigned short*)p; p += (size_t)M * C * 2;
  unsigned short* wqkvb = (unsigned short*)p; p += (size_t)N1 * C * 2;
  unsigned short* woutb = (unsigned short*)p; p += (size_t)C * C * 2;
  unsigned short* qkv   = (unsigned short*)p; p += (size_t)M * N1 * 2;
  unsigned short* Qr    = (unsigned short*)p; p += (size_t)M * C * 2;
  unsigned short* Kr    = (unsigned short*)p; p += (size_t)M * C * 2;
  unsigned short* Vt    = (unsigned short*)p; p += (size_t)M * C * 2;
  unsigned short* Ob    = xb;  // xb dead after QKV GEMM

  const long ncast = (long)M * C + (long)N1 * C + (long)C * C;  // 25165824
  cast3_kernel<<<(int)(ncast / 1024), 256, 0, stream>>>(x, Wqkv, Wout, xb);

  gemm128<0><<<dim3((M / 128) * (N1 / 256)), 512, 0, stream>>>(xb, wqkvb, bqkv, qkv, M, N1, C);

  prep_kernel<<<dim3(T / 64, 32), 256, 0, stream>>>(qkv, Qr, Kr, Vt);

  attn_fwd<<<dim3(32, T / 64), 256, 0, stream>>>(Qr, Kr, Vt, Ob, T);

  gemm128<1><<<dim3((M / 128) * (C / 256)), 512, 0, stream>>>(Ob, woutb, bout, out, M, C, C);
}